// Round 1
// baseline (4007.831 us; speedup 1.0000x reference)
//
#include <hip/hip_runtime.h>

// Problem: T=128, N=1024, H=256, L=64, C=64, V=1000.
// Restructure: everything batched except two per-batch-row GRU scans.

typedef unsigned short u16;
typedef __attribute__((ext_vector_type(8))) short bf16x8;   // 8 bf16 = 4 VGPR
typedef __attribute__((ext_vector_type(4))) float f32x4;

#define DEVFN static __device__ __forceinline__

DEVFN float b2f(u16 h){ union{unsigned u; float f;} v; v.u = ((unsigned)h) << 16; return v.f; }
DEVFN u16 f2b(float f){ union{float f; unsigned u;} v; v.f = f;
  return (u16)((v.u + 0x7fffu + ((v.u >> 16) & 1u)) >> 16); }

DEVFN f32x4 mfma16(bf16x8 a, bf16x8 b, f32x4 c){
  // inline asm (HipKittens pattern) — avoids builtin operand-type ambiguity
  asm("v_mfma_f32_16x16x32_bf16 %0, %1, %2, %0" : "+v"(c) : "v"(a), "v"(b));
  return c;
}
DEVFN void gl_lds16(const void* g, void* l){
  __builtin_amdgcn_global_load_lds((const __attribute__((address_space(1))) void*)g,
                                   (__attribute__((address_space(3))) void*)l, 16, 0, 0);
}
DEVFN float sigm(float x){ return __builtin_amdgcn_rcpf(1.0f + __expf(-x)); }
DEVFN float tanhf_(float x){ float e = __expf(2.0f * x); return 1.0f - 2.0f * __builtin_amdgcn_rcpf(e + 1.0f); }

// ---------------- small converters / gathers ----------------

__global__ __launch_bounds__(256) void k_f2b(const float* __restrict__ s, u16* __restrict__ d, int n){
  int i = blockIdx.x * 256 + threadIdx.x;
  if (i < n) d[i] = f2b(s[i]);
}

// Mh[n*64+l][256] = bf16(emb[lines[n*64+l]][:])   (2,097,152 8-elem chunks)
__global__ __launch_bounds__(256) void k_embed(const float* __restrict__ emb, const int* __restrict__ lines,
                                               u16* __restrict__ Mh){
  int c = blockIdx.x * 256 + threadIdx.x;
  int row = c >> 5;
  int j = (c & 31) * 8;
  int line = lines[row];
  const float* s = emb + line * 256 + j;
  bf16x8 v;
  #pragma unroll
  for (int q = 0; q < 8; q++) v[q] = (short)f2b(s[q]);
  *(bf16x8*)&Mh[row * 256 + j] = v;
}

// XA[t*N+n][0:64)=bf16(cond), [64:320)=Mh[n][prev_action]  (5,242,880 chunks)
__global__ __launch_bounds__(256) void k_xa(const float* __restrict__ cond, const u16* __restrict__ Mh,
                                            const int* __restrict__ actions, u16* __restrict__ XA){
  int c = blockIdx.x * 256 + threadIdx.x;
  int tn = c / 40;
  int j = (c - tn * 40) * 8;
  bf16x8 v;
  if (j < 64){
    const float* s = cond + tn * 64 + j;
    #pragma unroll
    for (int q = 0; q < 8; q++) v[q] = (short)f2b(s[q]);
  } else {
    int t = tn >> 10, n = tn & 1023;
    int idx = t ? actions[(t - 1) * 1024 + n] : 0;   // p0 = one_hot(0)
    v = *(const bf16x8*)&Mh[(n * 64 + idx) * 256 + (j - 64)];
  }
  *(bf16x8*)&XA[tn * 320 + j] = v;
}

// ---------------- m97-style 128x128 NT GEMM, bf16 in/out, f32 acc ----------------
// C[m][nc] = sum_k A[m][k] * B[nc][k]  (+bias, relu, optional row remap t*N+n -> n*T+t)

template<bool BIAS, bool RELU, bool REMAP>
__global__ __launch_bounds__(256) void k_gemm(const u16* __restrict__ A, int lda,
                                              const u16* __restrict__ B, int ldb,
                                              const float* __restrict__ bias,
                                              u16* __restrict__ C, int ldc, int K){
  __shared__ __align__(16) u16 sA[4096], sB[4096];
  const int tid = threadIdx.x, wid = tid >> 6, l = tid & 63;
  const int l15 = l & 15, l4 = l >> 4;
  const int m0 = blockIdx.x * 128, n0 = blockIdx.y * 128;
  const int wm = (wid >> 1) * 64, wn = (wid & 1) * 64;
  const int srow = wid * 16 + (l >> 2), scol = (l & 3) * 8;
  f32x4 acc[4][4] = {};
  for (int k0 = 0; k0 < K; k0 += 32){
    gl_lds16(&A[(m0 + srow) * lda + k0 + scol],      (char*)sA + wid * 1024);
    gl_lds16(&A[(m0 + 64 + srow) * lda + k0 + scol], (char*)sA + 4096 + wid * 1024);
    gl_lds16(&B[(n0 + srow) * ldb + k0 + scol],      (char*)sB + wid * 1024);
    gl_lds16(&B[(n0 + 64 + srow) * ldb + k0 + scol], (char*)sB + 4096 + wid * 1024);
    __syncthreads();
    bf16x8 af[4], bfr[4];
    #pragma unroll
    for (int i = 0; i < 4; i++) af[i]  = *(const bf16x8*)&sA[(wm + i * 16 + l15) * 32 + l4 * 8];
    #pragma unroll
    for (int j = 0; j < 4; j++) bfr[j] = *(const bf16x8*)&sB[(wn + j * 16 + l15) * 32 + l4 * 8];
    #pragma unroll
    for (int i = 0; i < 4; i++)
      #pragma unroll
      for (int j = 0; j < 4; j++)
        acc[i][j] = mfma16(af[i], bfr[j], acc[i][j]);
    __syncthreads();
  }
  #pragma unroll
  for (int i = 0; i < 4; i++)
    #pragma unroll
    for (int j = 0; j < 4; j++){
      int col = n0 + wn + j * 16 + l15;
      float bia = 0.f;
      if constexpr (BIAS) bia = bias[col];
      #pragma unroll
      for (int r = 0; r < 4; r++){
        int row = m0 + wm + i * 16 + l4 * 4 + r;       // D: row=(lane>>4)*4+reg, col=lane&15
        float v = acc[i][j][r] + bia;
        if constexpr (RELU) v = fmaxf(v, 0.f);
        int orow = row;
        if constexpr (REMAP) orow = ((row & 1023) << 7) | (row >> 10);  // t*N+n -> n*128+t
        C[(size_t)orow * ldc + col] = f2b(v);
      }
    }
}

// ---------------- GRU scans: each wg owns 16 batch rows, h in LDS ----------------
// Per step: gh = h_bf16 @ Whh^T (16x768, K=256 MFMA, weights streamed from L2),
// gi preloaded from global (precomputed X@Wih^T), gates in f32, h stays in LDS f32.
// CELL=false: bidirectional line-GRU (grid 128: bit0=dir), writes K[n][l][dir*256+col]
// CELL=true : GRUCell over T (grid 64), writes Hh bf16 + h f32 into d_out.

template<bool CELL>
__global__ __launch_bounds__(256) void k_scan(
    const u16* __restrict__ Gf, const u16* __restrict__ Gb,
    const u16* __restrict__ Wf, const u16* __restrict__ Wb,
    const float* __restrict__ bihf, const float* __restrict__ bhhf,
    const float* __restrict__ bihb, const float* __restrict__ bhhb,
    u16* __restrict__ Ko, float* __restrict__ out){
  const int bid = blockIdx.x;
  int dir, n0, NSTEP;
  const u16 *G, *W; const float *bih, *bhh;
  if (CELL){ dir = 0; n0 = bid * 16; G = Gf; W = Wf; bih = bihf; bhh = bhhf; NSTEP = 128; }
  else { dir = bid & 1; n0 = (bid >> 1) * 16;
         G = dir ? Gb : Gf; W = dir ? Wb : Wf;
         bih = dir ? bihb : bihf; bhh = dir ? bhhb : bhhf; NSTEP = 64; }
  __shared__ __align__(16) float hf[16 * 257];     // padded f32 master copy
  __shared__ __align__(16) u16  hb[16 * 256];      // bf16, 16B-chunk XOR-swizzled
  const int tid = threadIdx.x, wid = tid >> 6, l = tid & 63;
  const int l15 = l & 15, l4 = l >> 4;
  for (int i = tid; i < 16 * 257; i += 256) hf[i] = 0.f;
  for (int i = tid; i < 16 * 256; i += 256) hb[i] = 0;
  int colj[4], wb_[3][4];
  float bi[3][4], bh[3][4];
  #pragma unroll
  for (int j = 0; j < 4; j++) colj[j] = (wid + 4 * j) * 16 + l15;
  #pragma unroll
  for (int g = 0; g < 3; g++)
    #pragma unroll
    for (int j = 0; j < 4; j++){
      int cc = g * 256 + colj[j];
      bi[g][j] = bih[cc]; bh[g][j] = bhh[cc];
      wb_[g][j] = cc * 256 + l4 * 8;
    }
  int nr[4];
  #pragma unroll
  for (int r = 0; r < 4; r++) nr[r] = n0 + l4 * 4 + r;
  __syncthreads();
  for (int s = 0; s < NSTEP; ++s){
    int lc = (!CELL && dir) ? (63 - s) : s;
    u16 gi[3][4][4];                                // issue gi loads early
    #pragma unroll
    for (int g = 0; g < 3; g++)
      #pragma unroll
      for (int j = 0; j < 4; j++)
        #pragma unroll
        for (int r = 0; r < 4; r++){
          int gidx = CELL ? (lc * 1024 + nr[r]) * 768 + g * 256 + colj[j]
                          : (nr[r] * 64 + lc) * 768 + g * 256 + colj[j];
          gi[g][j][r] = G[gidx];
        }
    bf16x8 af[8];                                   // A-frags: h rows, swizzled chunks
    #pragma unroll
    for (int kt = 0; kt < 8; kt++){
      int chunk = (kt * 4 + l4) ^ (l15 & 7);
      af[kt] = *(const bf16x8*)&hb[l15 * 256 + chunk * 8];
    }
    f32x4 acc[3][4];
    #pragma unroll
    for (int g = 0; g < 3; g++)
      #pragma unroll
      for (int j = 0; j < 4; j++){
        f32x4 ac = {0.f, 0.f, 0.f, 0.f};
        const u16* wp = W + wb_[g][j];
        #pragma unroll
        for (int kt = 0; kt < 8; kt++)
          ac = mfma16(af[kt], *(const bf16x8*)&wp[kt * 32], ac);
        acc[g][j] = ac;
      }
    __syncthreads();                                // all hb reads done before update
    #pragma unroll
    for (int j = 0; j < 4; j++){
      int col = colj[j];
      #pragma unroll
      for (int r = 0; r < 4; r++){
        int row = l4 * 4 + r;
        float xr = b2f(gi[0][j][r]) + bi[0][j] + acc[0][j][r] + bh[0][j];
        float xz = b2f(gi[1][j][r]) + bi[1][j] + acc[1][j][r] + bh[1][j];
        float rg = sigm(xr), zg = sigm(xz);
        float nn = tanhf_(b2f(gi[2][j][r]) + bi[2][j] + rg * (acc[2][j][r] + bh[2][j]));
        float ho = hf[row * 257 + col];
        float hv = (1.f - zg) * nn + zg * ho;
        hf[row * 257 + col] = hv;
        u16 hq = f2b(hv);
        hb[row * 256 + ((((col >> 3) ^ (row & 7)) << 3) | (col & 7))] = hq;
        if (CELL){
          Ko[(lc * 1024 + nr[r]) * 256 + col] = hq;
          out[(size_t)(lc * 1024 + nr[r]) * 386 + 2 + col] = hv;
        } else {
          Ko[(nr[r] * 64 + lc) * 512 + dir * 256 + col] = hq;
        }
      }
    }
    __syncthreads();
  }
}

// ---------------- per-n logits GEMM (128x64, K=512) + row softmax ----------------

__global__ __launch_bounds__(256) void k_logits(const u16* __restrict__ Kc, const u16* __restrict__ kT,
                                                float* __restrict__ out){
  int n = blockIdx.x;
  const int tid = threadIdx.x, wid = tid >> 6, l = tid & 63, l15 = l & 15, l4 = l >> 4;
  const u16* An = kT + n * 65536;    // [128 t][512]
  const u16* Bn = Kc + n * 32768;    // [64 l][512]
  f32x4 acc[2][4] = {};
  for (int kt = 0; kt < 16; ++kt){
    bf16x8 a0 = *(const bf16x8*)&An[(wid * 32 + l15) * 512 + kt * 32 + l4 * 8];
    bf16x8 a1 = *(const bf16x8*)&An[(wid * 32 + 16 + l15) * 512 + kt * 32 + l4 * 8];
    #pragma unroll
    for (int j = 0; j < 4; j++){
      bf16x8 b = *(const bf16x8*)&Bn[(j * 16 + l15) * 512 + kt * 32 + l4 * 8];
      acc[0][j] = mfma16(a0, b, acc[0][j]);
      acc[1][j] = mfma16(a1, b, acc[1][j]);
    }
  }
  #pragma unroll
  for (int i = 0; i < 2; i++)
    #pragma unroll
    for (int r = 0; r < 4; r++){
      float v0 = acc[i][0][r], v1 = acc[i][1][r], v2 = acc[i][2][r], v3 = acc[i][3][r];
      float mx = fmaxf(fmaxf(v0, v1), fmaxf(v2, v3));
      #pragma unroll
      for (int s2 = 1; s2 < 16; s2 <<= 1) mx = fmaxf(mx, __shfl_xor(mx, s2));
      float e0 = __expf(v0 - mx), e1 = __expf(v1 - mx), e2 = __expf(v2 - mx), e3 = __expf(v3 - mx);
      float sm = e0 + e1 + e2 + e3;
      #pragma unroll
      for (int s2 = 1; s2 < 16; s2 <<= 1) sm += __shfl_xor(sm, s2);
      float rs = __builtin_amdgcn_rcpf(sm);
      int t = wid * 32 + i * 16 + l4 * 4 + r;
      float* o = out + (size_t)(t * 1024 + n) * 386 + 258;
      o[l15] = e0 * rs; o[16 + l15] = e1 * rs; o[32 + l15] = e2 * rs; o[48 + l15] = e3 * rs;
    }
}

// ---------------- a, v=critic(h), p=one_hot : one wave per (t,n) ----------------

__global__ __launch_bounds__(256) void k_pack(const int* __restrict__ actions,
                                              const float* __restrict__ cw, const float* __restrict__ cb,
                                              float* __restrict__ out){
  int idx = blockIdx.x * 4 + (threadIdx.x >> 6);
  int l = threadIdx.x & 63;
  float* o = out + (size_t)idx * 386;
  float s = 0.f;
  #pragma unroll
  for (int q = 0; q < 4; q++) s += o[2 + l + q * 64] * cw[l + q * 64];
  #pragma unroll
  for (int m = 32; m; m >>= 1) s += __shfl_down(s, m);
  int a = actions[idx];
  if (l == 0){ o[0] = (float)a; o[1] = s + cb[0]; }
  o[322 + l] = (l == a) ? 1.0f : 0.0f;
}

// ---------------- host ----------------

extern "C" void kernel_launch(void* const* d_in, const int* in_sizes, int n_in,
                              void* d_out, int out_size, void* d_ws, size_t ws_size,
                              hipStream_t stream){
  (void)in_sizes; (void)n_in; (void)out_size; (void)ws_size;
  const float* cond  = (const float*)d_in[0];
  const float* emb   = (const float*)d_in[1];
  const float* wih_f = (const float*)d_in[2];
  const float* whh_f = (const float*)d_in[3];
  const float* bih_f = (const float*)d_in[4];
  const float* bhh_f = (const float*)d_in[5];
  const float* wih_b = (const float*)d_in[6];
  const float* whh_b = (const float*)d_in[7];
  const float* bih_b = (const float*)d_in[8];
  const float* bhh_b = (const float*)d_in[9];
  const float* f_w0  = (const float*)d_in[10];
  const float* f_b0  = (const float*)d_in[11];
  const float* f_w1  = (const float*)d_in[12];
  const float* f_b1  = (const float*)d_in[13];
  const float* c_wih = (const float*)d_in[14];
  const float* c_whh = (const float*)d_in[15];
  const float* c_bih = (const float*)d_in[16];
  const float* c_bhh = (const float*)d_in[17];
  const float* actw  = (const float*)d_in[18];
  const float* actb  = (const float*)d_in[19];
  const float* cw    = (const float*)d_in[20];
  const float* cb    = (const float*)d_in[21];
  const int* lines   = (const int*)d_in[22];
  const int* actions = (const int*)d_in[23];
  float* out = (float*)d_out;

  char* ws = (char*)d_ws;
  size_t off = 0;
  auto alloc = [&](size_t b){ char* p = ws + off; off += (b + 255) & ~(size_t)255; return p; };
  u16* Mh  = (u16*)alloc((size_t)1024 * 64 * 256 * 2);   // 32 MiB embeddings bf16
  u16* Kc  = (u16*)alloc((size_t)1024 * 64 * 512 * 2);   // 64 MiB K=[Kf|Kb] bf16
  char* RA = alloc((size_t)128 * 1024 * 768 * 2);        // 192 MiB: Gf|Gb -> GI -> kT
  char* RD = alloc((size_t)128 * 1024 * 320 * 2);        // 80 MiB:  XA -> X -> Hh
  u16* X0  = (u16*)alloc((size_t)128 * 1024 * 256 * 2);  // 64 MiB
  u16* wihf_h = (u16*)alloc(196608 * 2);
  u16* whhf_h = (u16*)alloc(196608 * 2);
  u16* wihb_h = (u16*)alloc(196608 * 2);
  u16* whhb_h = (u16*)alloc(196608 * 2);
  u16* cwih_h = (u16*)alloc(196608 * 2);
  u16* cwhh_h = (u16*)alloc(196608 * 2);
  u16* fw0_h  = (u16*)alloc(81920 * 2);
  u16* fw1_h  = (u16*)alloc(65536 * 2);
  u16* actw_h = (u16*)alloc(131072 * 2);

  u16* Gf = (u16*)RA;
  u16* Gb = (u16*)(RA + (size_t)64 * 1024 * 768 * 2);
  u16* GI = (u16*)RA;
  u16* kT = (u16*)RA;
  u16* XA = (u16*)RD;
  u16* X  = (u16*)RD;
  u16* Hh = (u16*)RD;

  // 1. weights -> bf16
  const float* srcs[9] = {wih_f, whh_f, wih_b, whh_b, c_wih, c_whh, f_w0, f_w1, actw};
  u16* dsts[9] = {wihf_h, whhf_h, wihb_h, whhb_h, cwih_h, cwhh_h, fw0_h, fw1_h, actw_h};
  const int ns[9] = {196608,196608,196608,196608,196608,196608,81920,65536,131072};
  for (int i = 0; i < 9; i++)
    k_f2b<<<dim3((ns[i] + 255) / 256), dim3(256), 0, stream>>>(srcs[i], dsts[i], ns[i]);
  // 2. embedding gather
  k_embed<<<dim3(8192), dim3(256), 0, stream>>>(emb, lines, Mh);
  // 3/4. GRU input projections, both directions: [65536,256]@[256,768]
  k_gemm<false,false,false><<<dim3(512,6), dim3(256), 0, stream>>>(Mh, 256, wihf_h, 256, nullptr, Gf, 768, 256);
  k_gemm<false,false,false><<<dim3(512,6), dim3(256), 0, stream>>>(Mh, 256, wihb_h, 256, nullptr, Gb, 768, 256);
  // 5. bidirectional line-GRU scan -> Kc
  k_scan<false><<<dim3(128), dim3(256), 0, stream>>>(Gf, Gb, whhf_h, whhb_h, bih_f, bhh_f, bih_b, bhh_b, Kc, nullptr);
  // 6. pointer-read gather + cond concat (prev actions known upfront)
  k_xa<<<dim3(20480), dim3(256), 0, stream>>>(cond, Mh, actions, XA);
  // 7/8. MLP: relu(XA@W0^T+b0), relu(X0@W1^T+b1)
  k_gemm<true,true,false><<<dim3(1024,2), dim3(256), 0, stream>>>(XA, 320, fw0_h, 320, f_b0, X0, 256, 320);
  k_gemm<true,true,false><<<dim3(1024,2), dim3(256), 0, stream>>>(X0, 256, fw1_h, 256, f_b1, X, 256, 256);
  // 9. GRUCell input projections for all t
  k_gemm<false,false,false><<<dim3(1024,6), dim3(256), 0, stream>>>(X, 256, cwih_h, 256, nullptr, GI, 768, 256);
  // 10. GRUCell scan over T -> Hh bf16 + h f32 into d_out
  k_scan<true><<<dim3(64), dim3(256), 0, stream>>>(GI, nullptr, cwhh_h, nullptr, c_bih, c_bhh, nullptr, nullptr, Hh, out);
  // 11. actor: k = h@actor_w^T + b, stored transposed [n][t][512]
  k_gemm<true,false,true><<<dim3(1024,4), dim3(256), 0, stream>>>(Hh, 256, actw_h, 256, actb, kT, 512, 256);
  // 12. logits w = K.k + softmax -> probs into d_out
  k_logits<<<dim3(1024), dim3(256), 0, stream>>>(Kc, kT, out);
  // 13. a, v, one_hot(p)
  k_pack<<<dim3(32768), dim3(256), 0, stream>>>(actions, cw, cb, out);
  // 14. second output = hx[-1:]
  hipMemcpyAsync(out + (size_t)128 * 1024 * 386, out + (size_t)127 * 1024 * 386,
                 (size_t)1024 * 386 * 4, hipMemcpyDeviceToDevice, stream);
}

// Round 2
// 3089.084 us; speedup vs baseline: 1.2974x; 1.2974x over previous
//
#include <hip/hip_runtime.h>

// Problem: T=128, N=1024, H=256, L=64, C=64, V=1000.
// Restructure: everything batched except two per-batch-row GRU scans.
// R2: k_scan rewritten — 8 waves/block + register-prefetch of gi one step
// ahead (loads are recurrence-independent). R1 was HBM-latency-serialized
// (16.4us/step, 145 GB/s, occupancy 3%).

typedef unsigned short u16;
typedef __attribute__((ext_vector_type(8))) short bf16x8;   // 8 bf16 = 4 VGPR
typedef __attribute__((ext_vector_type(4))) float f32x4;

#define DEVFN static __device__ __forceinline__

DEVFN float b2f(u16 h){ union{unsigned u; float f;} v; v.u = ((unsigned)h) << 16; return v.f; }
DEVFN u16 f2b(float f){ union{float f; unsigned u;} v; v.f = f;
  return (u16)((v.u + 0x7fffu + ((v.u >> 16) & 1u)) >> 16); }

DEVFN f32x4 mfma16(bf16x8 a, bf16x8 b, f32x4 c){
  asm("v_mfma_f32_16x16x32_bf16 %0, %1, %2, %0" : "+v"(c) : "v"(a), "v"(b));
  return c;
}
DEVFN void gl_lds16(const void* g, void* l){
  __builtin_amdgcn_global_load_lds((const __attribute__((address_space(1))) void*)g,
                                   (__attribute__((address_space(3))) void*)l, 16, 0, 0);
}
DEVFN float sigm(float x){ return __builtin_amdgcn_rcpf(1.0f + __expf(-x)); }
DEVFN float tanhf_(float x){ float e = __expf(2.0f * x); return 1.0f - 2.0f * __builtin_amdgcn_rcpf(e + 1.0f); }

// ---------------- small converters / gathers ----------------

__global__ __launch_bounds__(256) void k_f2b(const float* __restrict__ s, u16* __restrict__ d, int n){
  int i = blockIdx.x * 256 + threadIdx.x;
  if (i < n) d[i] = f2b(s[i]);
}

__global__ __launch_bounds__(256) void k_embed(const float* __restrict__ emb, const int* __restrict__ lines,
                                               u16* __restrict__ Mh){
  int c = blockIdx.x * 256 + threadIdx.x;
  int row = c >> 5;
  int j = (c & 31) * 8;
  int line = lines[row];
  const float* s = emb + line * 256 + j;
  bf16x8 v;
  #pragma unroll
  for (int q = 0; q < 8; q++) v[q] = (short)f2b(s[q]);
  *(bf16x8*)&Mh[row * 256 + j] = v;
}

__global__ __launch_bounds__(256) void k_xa(const float* __restrict__ cond, const u16* __restrict__ Mh,
                                            const int* __restrict__ actions, u16* __restrict__ XA){
  int c = blockIdx.x * 256 + threadIdx.x;
  int tn = c / 40;
  int j = (c - tn * 40) * 8;
  bf16x8 v;
  if (j < 64){
    const float* s = cond + tn * 64 + j;
    #pragma unroll
    for (int q = 0; q < 8; q++) v[q] = (short)f2b(s[q]);
  } else {
    int t = tn >> 10, n = tn & 1023;
    int idx = t ? actions[(t - 1) * 1024 + n] : 0;   // p0 = one_hot(0)
    v = *(const bf16x8*)&Mh[(n * 64 + idx) * 256 + (j - 64)];
  }
  *(bf16x8*)&XA[tn * 320 + j] = v;
}

// ---------------- m97-style 128x128 NT GEMM, bf16 in/out, f32 acc ----------------

template<bool BIAS, bool RELU, bool REMAP>
__global__ __launch_bounds__(256) void k_gemm(const u16* __restrict__ A, int lda,
                                              const u16* __restrict__ B, int ldb,
                                              const float* __restrict__ bias,
                                              u16* __restrict__ C, int ldc, int K){
  __shared__ __align__(16) u16 sA[4096], sB[4096];
  const int tid = threadIdx.x, wid = tid >> 6, l = tid & 63;
  const int l15 = l & 15, l4 = l >> 4;
  const int m0 = blockIdx.x * 128, n0 = blockIdx.y * 128;
  const int wm = (wid >> 1) * 64, wn = (wid & 1) * 64;
  const int srow = wid * 16 + (l >> 2), scol = (l & 3) * 8;
  f32x4 acc[4][4] = {};
  for (int k0 = 0; k0 < K; k0 += 32){
    gl_lds16(&A[(m0 + srow) * lda + k0 + scol],      (char*)sA + wid * 1024);
    gl_lds16(&A[(m0 + 64 + srow) * lda + k0 + scol], (char*)sA + 4096 + wid * 1024);
    gl_lds16(&B[(n0 + srow) * ldb + k0 + scol],      (char*)sB + wid * 1024);
    gl_lds16(&B[(n0 + 64 + srow) * ldb + k0 + scol], (char*)sB + 4096 + wid * 1024);
    __syncthreads();
    bf16x8 af[4], bfr[4];
    #pragma unroll
    for (int i = 0; i < 4; i++) af[i]  = *(const bf16x8*)&sA[(wm + i * 16 + l15) * 32 + l4 * 8];
    #pragma unroll
    for (int j = 0; j < 4; j++) bfr[j] = *(const bf16x8*)&sB[(wn + j * 16 + l15) * 32 + l4 * 8];
    #pragma unroll
    for (int i = 0; i < 4; i++)
      #pragma unroll
      for (int j = 0; j < 4; j++)
        acc[i][j] = mfma16(af[i], bfr[j], acc[i][j]);
    __syncthreads();
  }
  #pragma unroll
  for (int i = 0; i < 4; i++)
    #pragma unroll
    for (int j = 0; j < 4; j++){
      int col = n0 + wn + j * 16 + l15;
      float bia = 0.f;
      if constexpr (BIAS) bia = bias[col];
      #pragma unroll
      for (int r = 0; r < 4; r++){
        int row = m0 + wm + i * 16 + l4 * 4 + r;       // D: row=(lane>>4)*4+reg, col=lane&15
        float v = acc[i][j][r] + bia;
        if constexpr (RELU) v = fmaxf(v, 0.f);
        int orow = row;
        if constexpr (REMAP) orow = ((row & 1023) << 7) | (row >> 10);  // t*N+n -> n*128+t
        C[(size_t)orow * ldc + col] = f2b(v);
      }
    }
}

// ---------------- GRU scans: each wg owns 16 batch rows, h in LDS ----------------
// 8 waves x 64 lanes. Per wave: 2 h-col-tiles x 3 gates = 6 accumulators.
// gi (precomputed X@Wih^T) register-prefetched one step ahead (recurrence-
// independent loads). Whh streamed from L2 each step. h: f32 master in LDS
// (padded), bf16 copy XOR-chunk-swizzled for conflict-free MFMA A-frag reads.

template<bool CELL>
__global__ __launch_bounds__(512) void k_scan(
    const u16* __restrict__ Gf, const u16* __restrict__ Gb,
    const u16* __restrict__ Wf, const u16* __restrict__ Wb,
    const float* __restrict__ bihf, const float* __restrict__ bhhf,
    const float* __restrict__ bihb, const float* __restrict__ bhhb,
    u16* __restrict__ Ko, float* __restrict__ out){
  const int bid = blockIdx.x;
  int dir, n0, NSTEP;
  const u16 *G, *W; const float *bih, *bhh;
  if (CELL){ dir = 0; n0 = bid * 16; G = Gf; W = Wf; bih = bihf; bhh = bhhf; NSTEP = 128; }
  else { dir = bid & 1; n0 = (bid >> 1) * 16;
         G = dir ? Gb : Gf; W = dir ? Wb : Wf;
         bih = dir ? bihb : bihf; bhh = dir ? bhhb : bhhf; NSTEP = 64; }
  __shared__ __align__(16) float hf[16 * 257];     // padded f32 master copy
  __shared__ __align__(16) u16  hb[16 * 256];      // bf16, 16B-chunk XOR-swizzled
  const int tid = threadIdx.x, wid = tid >> 6, l = tid & 63;
  const int l15 = l & 15, l4 = l >> 4;
  for (int i = tid; i < 16 * 257; i += 512) hf[i] = 0.f;
  for (int i = tid; i < 16 * 256; i += 512) hb[i] = 0;
  int colj[2], wb_[3][2];
  float bi[3][2], bh[3][2];
  #pragma unroll
  for (int j = 0; j < 2; j++) colj[j] = (wid + 8 * j) * 16 + l15;
  #pragma unroll
  for (int g = 0; g < 3; g++)
    #pragma unroll
    for (int j = 0; j < 2; j++){
      int cc = g * 256 + colj[j];
      bi[g][j] = bih[cc]; bh[g][j] = bhh[cc];
      wb_[g][j] = cc * 256 + l4 * 8;
    }
  int nr[4];
  #pragma unroll
  for (int r = 0; r < 4; r++) nr[r] = n0 + l4 * 4 + r;

  u16 gi_cur[3][2][4], gi_nxt[3][2][4];
  auto gidx = [&](int lc, int g, int j, int r){
    return CELL ? ((size_t)(lc * 1024 + nr[r]) * 768 + g * 256 + colj[j])
                : ((size_t)(nr[r] * 64 + lc) * 768 + g * 256 + colj[j]);
  };
  {
    int lc0 = (!CELL && dir) ? 63 : 0;
    #pragma unroll
    for (int g = 0; g < 3; g++)
      #pragma unroll
      for (int j = 0; j < 2; j++)
        #pragma unroll
        for (int r = 0; r < 4; r++)
          gi_cur[g][j][r] = G[gidx(lc0, g, j, r)];
  }
  __syncthreads();

  for (int s = 0; s < NSTEP; ++s){
    int lc = (!CELL && dir) ? (63 - s) : s;
    if (s + 1 < NSTEP){                              // prefetch next step's gi
      int lcn = (!CELL && dir) ? (63 - (s + 1)) : (s + 1);
      #pragma unroll
      for (int g = 0; g < 3; g++)
        #pragma unroll
        for (int j = 0; j < 2; j++)
          #pragma unroll
          for (int r = 0; r < 4; r++)
            gi_nxt[g][j][r] = G[gidx(lcn, g, j, r)];
    }
    bf16x8 af[8];                                    // A-frags: h rows, swizzled chunks
    #pragma unroll
    for (int kt = 0; kt < 8; kt++){
      int chunk = (kt * 4 + l4) ^ (l15 & 7);
      af[kt] = *(const bf16x8*)&hb[l15 * 256 + chunk * 8];
    }
    f32x4 acc[3][2];
    #pragma unroll
    for (int g = 0; g < 3; g++)
      #pragma unroll
      for (int j = 0; j < 2; j++){
        f32x4 ac = {0.f, 0.f, 0.f, 0.f};
        const u16* wp = W + wb_[g][j];
        #pragma unroll
        for (int kt = 0; kt < 8; kt++)
          ac = mfma16(af[kt], *(const bf16x8*)&wp[kt * 32], ac);
        acc[g][j] = ac;
      }
    __syncthreads();                                 // all hb reads done before update
    #pragma unroll
    for (int j = 0; j < 2; j++){
      int col = colj[j];
      #pragma unroll
      for (int r = 0; r < 4; r++){
        int row = l4 * 4 + r;
        float xr = b2f(gi_cur[0][j][r]) + bi[0][j] + acc[0][j][r] + bh[0][j];
        float xz = b2f(gi_cur[1][j][r]) + bi[1][j] + acc[1][j][r] + bh[1][j];
        float rg = sigm(xr), zg = sigm(xz);
        float nn = tanhf_(b2f(gi_cur[2][j][r]) + bi[2][j] + rg * (acc[2][j][r] + bh[2][j]));
        float ho = hf[row * 257 + col];
        float hv = (1.f - zg) * nn + zg * ho;
        hf[row * 257 + col] = hv;
        u16 hq = f2b(hv);
        hb[row * 256 + ((((col >> 3) ^ (row & 7)) << 3) | (col & 7))] = hq;
        if (CELL){
          Ko[(size_t)(lc * 1024 + nr[r]) * 256 + col] = hq;
          out[(size_t)(lc * 1024 + nr[r]) * 386 + 2 + col] = hv;
        } else {
          Ko[(size_t)(nr[r] * 64 + lc) * 512 + dir * 256 + col] = hq;
        }
      }
    }
    __syncthreads();
    #pragma unroll
    for (int g = 0; g < 3; g++)
      #pragma unroll
      for (int j = 0; j < 2; j++)
        #pragma unroll
        for (int r = 0; r < 4; r++)
          gi_cur[g][j][r] = gi_nxt[g][j][r];
  }
}

// ---------------- per-n logits GEMM (128x64, K=512) + row softmax ----------------

__global__ __launch_bounds__(256) void k_logits(const u16* __restrict__ Kc, const u16* __restrict__ kT,
                                                float* __restrict__ out){
  int n = blockIdx.x;
  const int tid = threadIdx.x, wid = tid >> 6, l = tid & 63, l15 = l & 15, l4 = l >> 4;
  const u16* An = kT + n * 65536;    // [128 t][512]
  const u16* Bn = Kc + n * 32768;    // [64 l][512]
  f32x4 acc[2][4] = {};
  for (int kt = 0; kt < 16; ++kt){
    bf16x8 a0 = *(const bf16x8*)&An[(wid * 32 + l15) * 512 + kt * 32 + l4 * 8];
    bf16x8 a1 = *(const bf16x8*)&An[(wid * 32 + 16 + l15) * 512 + kt * 32 + l4 * 8];
    #pragma unroll
    for (int j = 0; j < 4; j++){
      bf16x8 b = *(const bf16x8*)&Bn[(j * 16 + l15) * 512 + kt * 32 + l4 * 8];
      acc[0][j] = mfma16(a0, b, acc[0][j]);
      acc[1][j] = mfma16(a1, b, acc[1][j]);
    }
  }
  #pragma unroll
  for (int i = 0; i < 2; i++)
    #pragma unroll
    for (int r = 0; r < 4; r++){
      float v0 = acc[i][0][r], v1 = acc[i][1][r], v2 = acc[i][2][r], v3 = acc[i][3][r];
      float mx = fmaxf(fmaxf(v0, v1), fmaxf(v2, v3));
      #pragma unroll
      for (int s2 = 1; s2 < 16; s2 <<= 1) mx = fmaxf(mx, __shfl_xor(mx, s2));
      float e0 = __expf(v0 - mx), e1 = __expf(v1 - mx), e2 = __expf(v2 - mx), e3 = __expf(v3 - mx);
      float sm = e0 + e1 + e2 + e3;
      #pragma unroll
      for (int s2 = 1; s2 < 16; s2 <<= 1) sm += __shfl_xor(sm, s2);
      float rs = __builtin_amdgcn_rcpf(sm);
      int t = wid * 32 + i * 16 + l4 * 4 + r;
      float* o = out + (size_t)(t * 1024 + n) * 386 + 258;
      o[l15] = e0 * rs; o[16 + l15] = e1 * rs; o[32 + l15] = e2 * rs; o[48 + l15] = e3 * rs;
    }
}

// ---------------- a, v=critic(h), p=one_hot : one wave per (t,n) ----------------

__global__ __launch_bounds__(256) void k_pack(const int* __restrict__ actions,
                                              const float* __restrict__ cw, const float* __restrict__ cb,
                                              float* __restrict__ out){
  int idx = blockIdx.x * 4 + (threadIdx.x >> 6);
  int l = threadIdx.x & 63;
  float* o = out + (size_t)idx * 386;
  float s = 0.f;
  #pragma unroll
  for (int q = 0; q < 4; q++) s += o[2 + l + q * 64] * cw[l + q * 64];
  #pragma unroll
  for (int m = 32; m; m >>= 1) s += __shfl_down(s, m);
  int a = actions[idx];
  if (l == 0){ o[0] = (float)a; o[1] = s + cb[0]; }
  o[322 + l] = (l == a) ? 1.0f : 0.0f;
}

// ---------------- host ----------------

extern "C" void kernel_launch(void* const* d_in, const int* in_sizes, int n_in,
                              void* d_out, int out_size, void* d_ws, size_t ws_size,
                              hipStream_t stream){
  (void)in_sizes; (void)n_in; (void)out_size; (void)ws_size;
  const float* cond  = (const float*)d_in[0];
  const float* emb   = (const float*)d_in[1];
  const float* wih_f = (const float*)d_in[2];
  const float* whh_f = (const float*)d_in[3];
  const float* bih_f = (const float*)d_in[4];
  const float* bhh_f = (const float*)d_in[5];
  const float* wih_b = (const float*)d_in[6];
  const float* whh_b = (const float*)d_in[7];
  const float* bih_b = (const float*)d_in[8];
  const float* bhh_b = (const float*)d_in[9];
  const float* f_w0  = (const float*)d_in[10];
  const float* f_b0  = (const float*)d_in[11];
  const float* f_w1  = (const float*)d_in[12];
  const float* f_b1  = (const float*)d_in[13];
  const float* c_wih = (const float*)d_in[14];
  const float* c_whh = (const float*)d_in[15];
  const float* c_bih = (const float*)d_in[16];
  const float* c_bhh = (const float*)d_in[17];
  const float* actw  = (const float*)d_in[18];
  const float* actb  = (const float*)d_in[19];
  const float* cw    = (const float*)d_in[20];
  const float* cb    = (const float*)d_in[21];
  const int* lines   = (const int*)d_in[22];
  const int* actions = (const int*)d_in[23];
  float* out = (float*)d_out;

  char* ws = (char*)d_ws;
  size_t off = 0;
  auto alloc = [&](size_t b){ char* p = ws + off; off += (b + 255) & ~(size_t)255; return p; };
  u16* Mh  = (u16*)alloc((size_t)1024 * 64 * 256 * 2);   // 32 MiB embeddings bf16
  u16* Kc  = (u16*)alloc((size_t)1024 * 64 * 512 * 2);   // 64 MiB K=[Kf|Kb] bf16
  char* RA = alloc((size_t)128 * 1024 * 768 * 2);        // 192 MiB: Gf|Gb -> GI -> kT
  char* RD = alloc((size_t)128 * 1024 * 320 * 2);        // 80 MiB:  XA -> X -> Hh
  u16* X0  = (u16*)alloc((size_t)128 * 1024 * 256 * 2);  // 64 MiB
  u16* wihf_h = (u16*)alloc(196608 * 2);
  u16* whhf_h = (u16*)alloc(196608 * 2);
  u16* wihb_h = (u16*)alloc(196608 * 2);
  u16* whhb_h = (u16*)alloc(196608 * 2);
  u16* cwih_h = (u16*)alloc(196608 * 2);
  u16* cwhh_h = (u16*)alloc(196608 * 2);
  u16* fw0_h  = (u16*)alloc(81920 * 2);
  u16* fw1_h  = (u16*)alloc(65536 * 2);
  u16* actw_h = (u16*)alloc(131072 * 2);

  u16* Gf = (u16*)RA;
  u16* Gb = (u16*)(RA + (size_t)64 * 1024 * 768 * 2);
  u16* GI = (u16*)RA;
  u16* kT = (u16*)RA;
  u16* XA = (u16*)RD;
  u16* X  = (u16*)RD;
  u16* Hh = (u16*)RD;

  // 1. weights -> bf16
  const float* srcs[9] = {wih_f, whh_f, wih_b, whh_b, c_wih, c_whh, f_w0, f_w1, actw};
  u16* dsts[9] = {wihf_h, whhf_h, wihb_h, whhb_h, cwih_h, cwhh_h, fw0_h, fw1_h, actw_h};
  const int ns[9] = {196608,196608,196608,196608,196608,196608,81920,65536,131072};
  for (int i = 0; i < 9; i++)
    k_f2b<<<dim3((ns[i] + 255) / 256), dim3(256), 0, stream>>>(srcs[i], dsts[i], ns[i]);
  // 2. embedding gather
  k_embed<<<dim3(8192), dim3(256), 0, stream>>>(emb, lines, Mh);
  // 3/4. GRU input projections, both directions: [65536,256]@[256,768]
  k_gemm<false,false,false><<<dim3(512,6), dim3(256), 0, stream>>>(Mh, 256, wihf_h, 256, nullptr, Gf, 768, 256);
  k_gemm<false,false,false><<<dim3(512,6), dim3(256), 0, stream>>>(Mh, 256, wihb_h, 256, nullptr, Gb, 768, 256);
  // 5. bidirectional line-GRU scan -> Kc
  k_scan<false><<<dim3(128), dim3(512), 0, stream>>>(Gf, Gb, whhf_h, whhb_h, bih_f, bhh_f, bih_b, bhh_b, Kc, nullptr);
  // 6. pointer-read gather + cond concat (prev actions known upfront)
  k_xa<<<dim3(20480), dim3(256), 0, stream>>>(cond, Mh, actions, XA);
  // 7/8. MLP: relu(XA@W0^T+b0), relu(X0@W1^T+b1)
  k_gemm<true,true,false><<<dim3(1024,2), dim3(256), 0, stream>>>(XA, 320, fw0_h, 320, f_b0, X0, 256, 320);
  k_gemm<true,true,false><<<dim3(1024,2), dim3(256), 0, stream>>>(X0, 256, fw1_h, 256, f_b1, X, 256, 256);
  // 9. GRUCell input projections for all t
  k_gemm<false,false,false><<<dim3(1024,6), dim3(256), 0, stream>>>(X, 256, cwih_h, 256, nullptr, GI, 768, 256);
  // 10. GRUCell scan over T -> Hh bf16 + h f32 into d_out
  k_scan<true><<<dim3(64), dim3(512), 0, stream>>>(GI, nullptr, cwhh_h, nullptr, c_bih, c_bhh, nullptr, nullptr, Hh, out);
  // 11. actor: k = h@actor_w^T + b, stored transposed [n][t][512]
  k_gemm<true,false,true><<<dim3(1024,4), dim3(256), 0, stream>>>(Hh, 256, actw_h, 256, actb, kT, 512, 256);
  // 12. logits w = K.k + softmax -> probs into d_out
  k_logits<<<dim3(1024), dim3(256), 0, stream>>>(Kc, kT, out);
  // 13. a, v, one_hot(p)
  k_pack<<<dim3(32768), dim3(256), 0, stream>>>(actions, cw, cb, out);
  // 14. second output = hx[-1:]
  hipMemcpyAsync(out + (size_t)128 * 1024 * 386, out + (size_t)127 * 1024 * 386,
                 (size_t)1024 * 386 * 4, hipMemcpyDeviceToDevice, stream);
}

// Round 3
// 1418.919 us; speedup vs baseline: 2.8246x; 2.1771x over previous
//
#include <hip/hip_runtime.h>

// T=128, N=1024, H=256, L=64, C=64, V=1000.
// R3: scans restructured — Whh resident in VGPRs (loaded once), gi staged via
// global_load_lds double-buffer in producer-packed layout, hb double-buffered
// (1 barrier/step). R2 was latency-serialized on per-step weight+gi reloads.

typedef unsigned short u16;
typedef __attribute__((ext_vector_type(8))) short bf16x8;   // 8 bf16 = 4 VGPR
typedef __attribute__((ext_vector_type(4))) short bf16x4;   // 4 bf16 = 2 VGPR
typedef __attribute__((ext_vector_type(4))) float f32x4;

#define DEVFN static __device__ __forceinline__

DEVFN float b2f(u16 h){ union{unsigned u; float f;} v; v.u = ((unsigned)h) << 16; return v.f; }
DEVFN u16 f2b(float f){ union{float f; unsigned u;} v; v.f = f;
  return (u16)((v.u + 0x7fffu + ((v.u >> 16) & 1u)) >> 16); }

DEVFN f32x4 mfma16(bf16x8 a, bf16x8 b, f32x4 c){
  asm("v_mfma_f32_16x16x32_bf16 %0, %1, %2, %0" : "+v"(c) : "v"(a), "v"(b));
  return c;
}
DEVFN void gl_lds16(const void* g, void* l){
  __builtin_amdgcn_global_load_lds((const __attribute__((address_space(1))) void*)g,
                                   (__attribute__((address_space(3))) void*)l, 16, 0, 0);
}
DEVFN float sigm(float x){ return __builtin_amdgcn_rcpf(1.0f + __expf(-x)); }
DEVFN float tanhf_(float x){ float e = __expf(2.0f * x); return 1.0f - 2.0f * __builtin_amdgcn_rcpf(e + 1.0f); }

// ---------------- small converters / prep ----------------

__global__ __launch_bounds__(256) void k_f2b(const float* __restrict__ s, u16* __restrict__ d, int n){
  int i = blockIdx.x * 256 + threadIdx.x;
  if (i < n) d[i] = f2b(s[i]);
}

// bc[i] = bih[i] + (i<512 ? bhh[i] : 0)  (r,z biases pre-summed; n-gate keeps bhh separate)
__global__ __launch_bounds__(256) void k_bias(const float* __restrict__ bih, const float* __restrict__ bhh,
                                              float* __restrict__ dst){
  int i = blockIdx.x * 256 + threadIdx.x;
  if (i < 768) dst[i] = bih[i] + (i < 512 ? bhh[i] : 0.f);
}

// embedding gather; LMAJOR=false: Mh[n*64+l][256], LMAJOR=true: Mh2[l*1024+n][256]
template<bool LMAJOR>
__global__ __launch_bounds__(256) void k_embed(const float* __restrict__ emb, const int* __restrict__ lines,
                                               u16* __restrict__ Mh){
  int c = blockIdx.x * 256 + threadIdx.x;
  int row = c >> 5;
  int j = (c & 31) * 8;
  int n, ll;
  if (LMAJOR){ ll = row >> 10; n = row & 1023; } else { n = row >> 6; ll = row & 63; }
  int line = lines[n * 64 + ll];
  const float* s = emb + line * 256 + j;
  bf16x8 v;
  #pragma unroll
  for (int q = 0; q < 8; q++) v[q] = (short)f2b(s[q]);
  *(bf16x8*)&Mh[row * 256 + j] = v;
}

// XA[t*N+n][0:64)=bf16(cond), [64:320)=Mh[n][prev_action]
__global__ __launch_bounds__(256) void k_xa(const float* __restrict__ cond, const u16* __restrict__ Mh,
                                            const int* __restrict__ actions, u16* __restrict__ XA){
  int c = blockIdx.x * 256 + threadIdx.x;
  int tn = c / 40;
  int j = (c - tn * 40) * 8;
  bf16x8 v;
  if (j < 64){
    const float* s = cond + tn * 64 + j;
    #pragma unroll
    for (int q = 0; q < 8; q++) v[q] = (short)f2b(s[q]);
  } else {
    int t = tn >> 10, n = tn & 1023;
    int idx = t ? actions[(t - 1) * 1024 + n] : 0;   // p0 = one_hot(0)
    v = *(const bf16x8*)&Mh[(n * 64 + idx) * 256 + (j - 64)];
  }
  *(bf16x8*)&XA[tn * 320 + j] = v;
}

// ---------------- 128x128 NT GEMM, bf16 in/out, f32 acc ----------------
// MODE 0: C[row][col] plain.  MODE 1: kT remap row t*N+n -> n*128+t.
// MODE 2: scan-packed G write: row -> (t=row>>10, n=row&1023); element (row,col)
//   stored at ((t*64+nb)*12288 + sl4*64 + x*2048 + swid*256 + sl15*4 + r) u16,
//   where nb=n>>4, sl4=(n>>2)&3, r=n&3, x=blockIdx.x (col-block = g*2+sj),
//   swid=(colp>>4), sl15=colp&15, colp=col&127. 4 r-values packed as one 8B store.
template<int MODE, bool BIAS, bool RELU>
__global__ __launch_bounds__(256) void k_gemm(const u16* __restrict__ A, int lda,
                                              const u16* __restrict__ B, int ldb,
                                              const float* __restrict__ bias,
                                              u16* __restrict__ C, int ldc, int K){
  __shared__ __align__(16) u16 sA[4096], sB[4096];
  const int tid = threadIdx.x, wid = tid >> 6, l = tid & 63;
  const int l15 = l & 15, l4 = l >> 4;
  const int bxm = (MODE >= 2) ? blockIdx.y : blockIdx.x;
  const int bxn = (MODE >= 2) ? blockIdx.x : blockIdx.y;
  const int m0 = bxm * 128, n0 = bxn * 128;
  const int wm = (wid >> 1) * 64, wn = (wid & 1) * 64;
  const int srow = wid * 16 + (l >> 2), scol = (l & 3) * 8;
  f32x4 acc[4][4] = {};
  for (int k0 = 0; k0 < K; k0 += 32){
    gl_lds16(&A[(m0 + srow) * lda + k0 + scol],      (char*)sA + wid * 1024);
    gl_lds16(&A[(m0 + 64 + srow) * lda + k0 + scol], (char*)sA + 4096 + wid * 1024);
    gl_lds16(&B[(n0 + srow) * ldb + k0 + scol],      (char*)sB + wid * 1024);
    gl_lds16(&B[(n0 + 64 + srow) * ldb + k0 + scol], (char*)sB + 4096 + wid * 1024);
    __syncthreads();
    bf16x8 af[4], bfr[4];
    #pragma unroll
    for (int i = 0; i < 4; i++) af[i]  = *(const bf16x8*)&sA[(wm + i * 16 + l15) * 32 + l4 * 8];
    #pragma unroll
    for (int j = 0; j < 4; j++) bfr[j] = *(const bf16x8*)&sB[(wn + j * 16 + l15) * 32 + l4 * 8];
    #pragma unroll
    for (int i = 0; i < 4; i++)
      #pragma unroll
      for (int j = 0; j < 4; j++)
        acc[i][j] = mfma16(af[i], bfr[j], acc[i][j]);
    __syncthreads();
  }
  if constexpr (MODE >= 2){
    #pragma unroll
    for (int j = 0; j < 4; j++){
      int colp = wn + j * 16 + l15;                 // 0..127 within this col-block
      float bia = BIAS ? bias[n0 + colp] : 0.f;
      size_t cpart = (size_t)blockIdx.x * 2048 + (size_t)(colp >> 4) * 256 + (size_t)(colp & 15) * 4;
      #pragma unroll
      for (int i = 0; i < 4; i++){
        int row = m0 + wm + i * 16 + l4 * 4;        // r=0 base; n&3==0 here
        int t = row >> 10, n = row & 1023;
        size_t addr = ((size_t)t * 64 + (n >> 4)) * 12288 + (size_t)((n >> 2) & 3) * 64 + cpart;
        unsigned q0 = (unsigned)f2b(acc[i][j][0] + bia) | ((unsigned)f2b(acc[i][j][1] + bia) << 16);
        unsigned q1 = (unsigned)f2b(acc[i][j][2] + bia) | ((unsigned)f2b(acc[i][j][3] + bia) << 16);
        uint2 qq; qq.x = q0; qq.y = q1;
        *(uint2*)(C + addr) = qq;
      }
    }
  } else {
    #pragma unroll
    for (int i = 0; i < 4; i++)
      #pragma unroll
      for (int j = 0; j < 4; j++){
        int col = n0 + wn + j * 16 + l15;
        float bia = 0.f;
        if constexpr (BIAS) bia = bias[col];
        #pragma unroll
        for (int r = 0; r < 4; r++){
          int row = m0 + wm + i * 16 + l4 * 4 + r;
          float v = acc[i][j][r] + bia;
          if constexpr (RELU) v = fmaxf(v, 0.f);
          int orow = row;
          if constexpr (MODE == 1) orow = ((row & 1023) << 7) | (row >> 10);
          C[(size_t)orow * ldc + col] = f2b(v);
        }
      }
  }
}

// ---------------- GRU scans: Whh in VGPRs, gi via gl_lds dbuf, hb dbuf ----------------
// 8 waves x 64. Wave wid owns output cols {wid*16, (wid+8)*16}+l15 across 3 gates.
// Per step: issue gl_lds for next gi region; MFMA j=0 (12 acc) on hb[cb];
// gate j=0 (writes hb[cb^1]); MFMA j=1; gate j=1; one __syncthreads (its
// vmcnt(0)+lgkmcnt(0) drain is exactly the dbuf handoff we need).

template<bool CELL>
__global__ __launch_bounds__(512) void k_scan(
    const u16* __restrict__ Ga, const u16* __restrict__ Gbk,
    const u16* __restrict__ Wa, const u16* __restrict__ Wb,
    const float* __restrict__ bhha, const float* __restrict__ bhhb,
    u16* __restrict__ Ko, float* __restrict__ out)
{
  const int NSTEP = CELL ? 128 : 64;
  int dir = 0, nb = blockIdx.x;
  const u16 *G = Ga, *W = Wa; const float* bhh = bhha;
  if (!CELL){
    dir = blockIdx.x & 1; nb = blockIdx.x >> 1;
    if (dir){ G = Gbk; W = Wb; bhh = bhhb; }
  }
  const int n0 = nb * 16;
  __shared__ __align__(16) u16 hb[2][16 * 256];
  __shared__ __align__(16) u16 gib[2][12288];
  const int tid = threadIdx.x, wid = tid >> 6, l = tid & 63;
  const int l15 = l & 15, l4 = l >> 4;
  for (int i = tid; i < 4096; i += 512) hb[0][i] = 0;
  const int col0 = wid * 16 + l15, col1 = (wid + 8) * 16 + l15;
  const float bhn0 = bhh[512 + col0], bhn1 = bhh[512 + col1];
  // resident weights: w[g][j][kt], lane l15 -> W-row, K-cols kt*32 + l4*8
  bf16x8 w[3][2][8];
  #pragma unroll
  for (int g = 0; g < 3; g++){
    #pragma unroll
    for (int j = 0; j < 2; j++){
      const u16* wp = W + ((size_t)(g * 256 + (j ? col1 : col0)) * 256 + l4 * 8);
      #pragma unroll
      for (int kt = 0; kt < 8; kt++) w[g][j][kt] = *(const bf16x8*)&wp[kt * 32];
    }
  }
  float h0[4] = {0.f,0.f,0.f,0.f}, h1[4] = {0.f,0.f,0.f,0.f};
  {  // prologue: stage gi for first step into gib[0]
    int lc0 = (!CELL && dir) ? 63 : 0;
    const char* src = (const char*)(G + ((size_t)lc0 * 64 + nb) * 12288);
    #pragma unroll
    for (int q = 0; q < 3; q++)
      gl_lds16(src + (wid * 3 + q) * 1024 + l * 16, (char*)&gib[0][(wid * 3 + q) * 512]);
  }
  __syncthreads();
  #pragma unroll 1
  for (int s = 0; s < NSTEP; ++s){
    const int cb = s & 1;
    const int lc = CELL ? s : (dir ? 63 - s : s);
    const int sn = (s + 1 < NSTEP) ? s + 1 : s;
    const int lcn = CELL ? sn : (dir ? 63 - sn : sn);
    {  // stage next step's gi
      const char* src = (const char*)(G + ((size_t)lcn * 64 + nb) * 12288);
      #pragma unroll
      for (int q = 0; q < 3; q++)
        gl_lds16(src + (wid * 3 + q) * 1024 + l * 16, (char*)&gib[cb ^ 1][(wid * 3 + q) * 512]);
    }
    // this step's gi: y[g*2+j][r]
    bf16x4 y[6];
    #pragma unroll
    for (int yy = 0; yy < 6; yy++)
      y[yy] = *(const bf16x4*)&gib[cb][yy * 2048 + tid * 4];
    // ---- j = 0 ----
    {
      f32x4 a0 = {0,0,0,0}, a1 = {0,0,0,0}, a2 = {0,0,0,0};
      #pragma unroll
      for (int kt = 0; kt < 8; kt++){
        int chunk = (kt * 4 + l4) ^ (l15 & 7);
        bf16x8 af = *(const bf16x8*)&hb[cb][l15 * 256 + chunk * 8];
        a0 = mfma16(af, w[0][0][kt], a0);
        a1 = mfma16(af, w[1][0][kt], a1);
        a2 = mfma16(af, w[2][0][kt], a2);
      }
      #pragma unroll
      for (int r = 0; r < 4; r++){
        int row = l4 * 4 + r;
        float xr = b2f((u16)y[0][r]) + a0[r];
        float xz = b2f((u16)y[2][r]) + a1[r];
        float rg = sigm(xr), zg = sigm(xz);
        float nn = tanhf_(b2f((u16)y[4][r]) + rg * (a2[r] + bhn0));
        float hv = (1.f - zg) * nn + zg * h0[r];
        h0[r] = hv;
        u16 hq = f2b(hv);
        hb[cb ^ 1][row * 256 + ((((col0 >> 3) ^ (row & 7)) << 3) | (col0 & 7))] = hq;
        if (CELL){
          size_t ro = (size_t)lc * 1024 + n0 + row;
          Ko[ro * 256 + col0] = hq;
          out[ro * 386 + 2 + col0] = hv;
        } else {
          Ko[((size_t)(n0 + row) * 64 + lc) * 512 + dir * 256 + col0] = hq;
        }
      }
    }
    // ---- j = 1 ----
    {
      f32x4 a0 = {0,0,0,0}, a1 = {0,0,0,0}, a2 = {0,0,0,0};
      #pragma unroll
      for (int kt = 0; kt < 8; kt++){
        int chunk = (kt * 4 + l4) ^ (l15 & 7);
        bf16x8 af = *(const bf16x8*)&hb[cb][l15 * 256 + chunk * 8];
        a0 = mfma16(af, w[0][1][kt], a0);
        a1 = mfma16(af, w[1][1][kt], a1);
        a2 = mfma16(af, w[2][1][kt], a2);
      }
      #pragma unroll
      for (int r = 0; r < 4; r++){
        int row = l4 * 4 + r;
        float xr = b2f((u16)y[1][r]) + a0[r];
        float xz = b2f((u16)y[3][r]) + a1[r];
        float rg = sigm(xr), zg = sigm(xz);
        float nn = tanhf_(b2f((u16)y[5][r]) + rg * (a2[r] + bhn1));
        float hv = (1.f - zg) * nn + zg * h1[r];
        h1[r] = hv;
        u16 hq = f2b(hv);
        hb[cb ^ 1][row * 256 + ((((col1 >> 3) ^ (row & 7)) << 3) | (col1 & 7))] = hq;
        if (CELL){
          size_t ro = (size_t)lc * 1024 + n0 + row;
          Ko[ro * 256 + col1] = hq;
          out[ro * 386 + 2 + col1] = hv;
        } else {
          Ko[((size_t)(n0 + row) * 64 + lc) * 512 + dir * 256 + col1] = hq;
        }
      }
    }
    __syncthreads();   // drains vmcnt (gi dbuf ready) + lgkmcnt (hb writes visible)
  }
}

// ---------------- per-n logits GEMM (128x64, K=512) + row softmax ----------------

__global__ __launch_bounds__(256) void k_logits(const u16* __restrict__ Kc, const u16* __restrict__ kT,
                                                float* __restrict__ out){
  int n = blockIdx.x;
  const int tid = threadIdx.x, wid = tid >> 6, l = tid & 63, l15 = l & 15, l4 = l >> 4;
  const u16* An = kT + n * 65536;    // [128 t][512]
  const u16* Bn = Kc + n * 32768;    // [64 l][512]
  f32x4 acc[2][4] = {};
  for (int kt = 0; kt < 16; ++kt){
    bf16x8 a0 = *(const bf16x8*)&An[(wid * 32 + l15) * 512 + kt * 32 + l4 * 8];
    bf16x8 a1 = *(const bf16x8*)&An[(wid * 32 + 16 + l15) * 512 + kt * 32 + l4 * 8];
    #pragma unroll
    for (int j = 0; j < 4; j++){
      bf16x8 b = *(const bf16x8*)&Bn[(j * 16 + l15) * 512 + kt * 32 + l4 * 8];
      acc[0][j] = mfma16(a0, b, acc[0][j]);
      acc[1][j] = mfma16(a1, b, acc[1][j]);
    }
  }
  #pragma unroll
  for (int i = 0; i < 2; i++)
    #pragma unroll
    for (int r = 0; r < 4; r++){
      float v0 = acc[i][0][r], v1 = acc[i][1][r], v2 = acc[i][2][r], v3 = acc[i][3][r];
      float mx = fmaxf(fmaxf(v0, v1), fmaxf(v2, v3));
      #pragma unroll
      for (int s2 = 1; s2 < 16; s2 <<= 1) mx = fmaxf(mx, __shfl_xor(mx, s2));
      float e0 = __expf(v0 - mx), e1 = __expf(v1 - mx), e2 = __expf(v2 - mx), e3 = __expf(v3 - mx);
      float sm = e0 + e1 + e2 + e3;
      #pragma unroll
      for (int s2 = 1; s2 < 16; s2 <<= 1) sm += __shfl_xor(sm, s2);
      float rs = __builtin_amdgcn_rcpf(sm);
      int t = wid * 32 + i * 16 + l4 * 4 + r;
      float* o = out + (size_t)(t * 1024 + n) * 386 + 258;
      o[l15] = e0 * rs; o[16 + l15] = e1 * rs; o[32 + l15] = e2 * rs; o[48 + l15] = e3 * rs;
    }
}

// ---------------- a, v=critic(h), p=one_hot ----------------

__global__ __launch_bounds__(256) void k_pack(const int* __restrict__ actions,
                                              const float* __restrict__ cw, const float* __restrict__ cb,
                                              float* __restrict__ out){
  int idx = blockIdx.x * 4 + (threadIdx.x >> 6);
  int l = threadIdx.x & 63;
  float* o = out + (size_t)idx * 386;
  float s = 0.f;
  #pragma unroll
  for (int q = 0; q < 4; q++) s += o[2 + l + q * 64] * cw[l + q * 64];
  #pragma unroll
  for (int m = 32; m; m >>= 1) s += __shfl_down(s, m);
  int a = actions[idx];
  if (l == 0){ o[0] = (float)a; o[1] = s + cb[0]; }
  o[322 + l] = (l == a) ? 1.0f : 0.0f;
}

// ---------------- host ----------------

extern "C" void kernel_launch(void* const* d_in, const int* in_sizes, int n_in,
                              void* d_out, int out_size, void* d_ws, size_t ws_size,
                              hipStream_t stream){
  (void)in_sizes; (void)n_in; (void)out_size; (void)ws_size;
  const float* cond  = (const float*)d_in[0];
  const float* emb   = (const float*)d_in[1];
  const float* wih_f = (const float*)d_in[2];
  const float* whh_f = (const float*)d_in[3];
  const float* bih_f = (const float*)d_in[4];
  const float* bhh_f = (const float*)d_in[5];
  const float* wih_b = (const float*)d_in[6];
  const float* whh_b = (const float*)d_in[7];
  const float* bih_b = (const float*)d_in[8];
  const float* bhh_b = (const float*)d_in[9];
  const float* f_w0  = (const float*)d_in[10];
  const float* f_b0  = (const float*)d_in[11];
  const float* f_w1  = (const float*)d_in[12];
  const float* f_b1  = (const float*)d_in[13];
  const float* c_wih = (const float*)d_in[14];
  const float* c_whh = (const float*)d_in[15];
  const float* c_bih = (const float*)d_in[16];
  const float* c_bhh = (const float*)d_in[17];
  const float* actw  = (const float*)d_in[18];
  const float* actb  = (const float*)d_in[19];
  const float* cw    = (const float*)d_in[20];
  const float* cbi   = (const float*)d_in[21];
  const int* lines   = (const int*)d_in[22];
  const int* actions = (const int*)d_in[23];
  float* out = (float*)d_out;

  char* ws = (char*)d_ws;
  size_t off = 0;
  auto alloc = [&](size_t b){ char* p = ws + off; off += (b + 255) & ~(size_t)255; return p; };
  u16* Mh  = (u16*)alloc((size_t)1024 * 64 * 256 * 2);   // 32 MiB, n-major
  u16* Kc  = (u16*)alloc((size_t)1024 * 64 * 512 * 2);   // 64 MiB
  char* RA = alloc((size_t)128 * 1024 * 768 * 2);        // 192 MiB: Gf|Gb -> GI -> kT
  char* RD = alloc((size_t)128 * 1024 * 320 * 2);        // 80 MiB:  XA -> X -> Hh
  u16* X0  = (u16*)alloc((size_t)128 * 1024 * 256 * 2);  // 64 MiB (also Mh2 early)
  u16* wihf_h = (u16*)alloc(196608 * 2);
  u16* whhf_h = (u16*)alloc(196608 * 2);
  u16* wihb_h = (u16*)alloc(196608 * 2);
  u16* whhb_h = (u16*)alloc(196608 * 2);
  u16* cwih_h = (u16*)alloc(196608 * 2);
  u16* cwhh_h = (u16*)alloc(196608 * 2);
  u16* fw0_h  = (u16*)alloc(81920 * 2);
  u16* fw1_h  = (u16*)alloc(65536 * 2);
  u16* actw_h = (u16*)alloc(131072 * 2);
  float* bc_f = (float*)alloc(768 * 4);
  float* bc_b = (float*)alloc(768 * 4);
  float* bc_c = (float*)alloc(768 * 4);

  u16* Gf  = (u16*)RA;                                   // packed [l][nb][...] 96 MiB
  u16* Gb  = (u16*)(RA + (size_t)64 * 1024 * 768 * 2);   // packed 96 MiB
  u16* GI  = (u16*)RA;                                   // packed [t][nb][...] 192 MiB
  u16* kT  = (u16*)RA;
  u16* XA  = (u16*)RD;
  u16* X   = (u16*)RD;
  u16* Hh  = (u16*)RD;
  u16* Mh2 = X0;                                          // l-major embeddings (aliases X0)

  // 1. weights -> bf16
  const float* srcs[9] = {wih_f, whh_f, wih_b, whh_b, c_wih, c_whh, f_w0, f_w1, actw};
  u16* dsts[9] = {wihf_h, whhf_h, wihb_h, whhb_h, cwih_h, cwhh_h, fw0_h, fw1_h, actw_h};
  const int ns[9] = {196608,196608,196608,196608,196608,196608,81920,65536,131072};
  for (int i = 0; i < 9; i++)
    k_f2b<<<dim3((ns[i] + 255) / 256), dim3(256), 0, stream>>>(srcs[i], dsts[i], ns[i]);
  // 2. combined biases
  k_bias<<<dim3(3), dim3(256), 0, stream>>>(bih_f, bhh_f, bc_f);
  k_bias<<<dim3(3), dim3(256), 0, stream>>>(bih_b, bhh_b, bc_b);
  k_bias<<<dim3(3), dim3(256), 0, stream>>>(c_bih, c_bhh, bc_c);
  // 3. embedding gathers (n-major for k_xa, l-major for line GEMMs)
  k_embed<false><<<dim3(8192), dim3(256), 0, stream>>>(emb, lines, Mh);
  k_embed<true ><<<dim3(8192), dim3(256), 0, stream>>>(emb, lines, Mh2);
  // 4/5. line-GRU input projections -> packed Gf/Gb (bias folded)
  k_gemm<2,true,false><<<dim3(6,512), dim3(256), 0, stream>>>(Mh2, 256, wihf_h, 256, bc_f, Gf, 0, 256);
  k_gemm<2,true,false><<<dim3(6,512), dim3(256), 0, stream>>>(Mh2, 256, wihb_h, 256, bc_b, Gb, 0, 256);
  // 6. bidirectional line-GRU scan -> Kc
  k_scan<false><<<dim3(128), dim3(512), 0, stream>>>(Gf, Gb, whhf_h, whhb_h, bhh_f, bhh_b, Kc, nullptr);
  // 7. pointer-read gather + cond concat
  k_xa<<<dim3(20480), dim3(256), 0, stream>>>(cond, Mh, actions, XA);
  // 8/9. MLP
  k_gemm<0,true,true><<<dim3(1024,2), dim3(256), 0, stream>>>(XA, 320, fw0_h, 320, f_b0, X0, 256, 320);
  k_gemm<0,true,true><<<dim3(1024,2), dim3(256), 0, stream>>>(X0, 256, fw1_h, 256, f_b1, X, 256, 256);
  // 10. GRUCell input projections -> packed GI (bias folded)
  k_gemm<2,true,false><<<dim3(6,1024), dim3(256), 0, stream>>>(X, 256, cwih_h, 256, bc_c, GI, 0, 256);
  // 11. GRUCell scan over T -> Hh bf16 + h f32 into d_out
  k_scan<true><<<dim3(64), dim3(512), 0, stream>>>(GI, nullptr, cwhh_h, nullptr, c_bhh, nullptr, Hh, out);
  // 12. actor: kT = [n][t][512]
  k_gemm<1,true,false><<<dim3(1024,4), dim3(256), 0, stream>>>(Hh, 256, actw_h, 256, actb, kT, 512, 256);
  // 13. logits + softmax
  k_logits<<<dim3(1024), dim3(256), 0, stream>>>(Kc, kT, out);
  // 14. a, v, one_hot(p)
  k_pack<<<dim3(32768), dim3(256), 0, stream>>>(actions, cw, cbi, out);
  // 15. second output = hx[-1:]
  hipMemcpyAsync(out + (size_t)128 * 1024 * 386, out + (size_t)127 * 1024 * 386,
                 (size_t)1024 * 386 * 4, hipMemcpyDeviceToDevice, stream);
}

// Round 5
// 1354.611 us; speedup vs baseline: 2.9587x; 1.0475x over previous
//
#include <hip/hip_runtime.h>

// T=128, N=1024, H=256, L=64, C=64, V=1000.
// R5 == R4 resubmit (R4 hit GPUAcquisitionTimeout; never measured).
// R4: scan sync rewritten — raw s_barrier + counted vmcnt (stores never
// drained), cooperative vectorized Ko output via LDS (1 store/thread/step),
// af fragments reused across both col-tiles, out-h f32 expanded by k_hout.

typedef unsigned short u16;
typedef __attribute__((ext_vector_type(8))) short bf16x8;   // 8 bf16 = 4 VGPR
typedef __attribute__((ext_vector_type(4))) short bf16x4;   // 4 bf16 = 2 VGPR
typedef __attribute__((ext_vector_type(4))) float f32x4;

#define DEVFN static __device__ __forceinline__

DEVFN float b2f(u16 h){ union{unsigned u; float f;} v; v.u = ((unsigned)h) << 16; return v.f; }
DEVFN u16 f2b(float f){ union{float f; unsigned u;} v; v.f = f;
  return (u16)((v.u + 0x7fffu + ((v.u >> 16) & 1u)) >> 16); }

DEVFN f32x4 mfma16(bf16x8 a, bf16x8 b, f32x4 c){
  asm("v_mfma_f32_16x16x32_bf16 %0, %1, %2, %0" : "+v"(c) : "v"(a), "v"(b));
  return c;
}
DEVFN void gl_lds16(const void* g, void* l){
  __builtin_amdgcn_global_load_lds((const __attribute__((address_space(1))) void*)g,
                                   (__attribute__((address_space(3))) void*)l, 16, 0, 0);
}
DEVFN float sigm(float x){ return __builtin_amdgcn_rcpf(1.0f + __expf(-x)); }
DEVFN float tanhf_(float x){ float e = __expf(2.0f * x); return 1.0f - 2.0f * __builtin_amdgcn_rcpf(e + 1.0f); }

// ---------------- small converters / prep ----------------

__global__ __launch_bounds__(256) void k_f2b(const float* __restrict__ s, u16* __restrict__ d, int n){
  int i = blockIdx.x * 256 + threadIdx.x;
  if (i < n) d[i] = f2b(s[i]);
}

__global__ __launch_bounds__(256) void k_bias(const float* __restrict__ bih, const float* __restrict__ bhh,
                                              float* __restrict__ dst){
  int i = blockIdx.x * 256 + threadIdx.x;
  if (i < 768) dst[i] = bih[i] + (i < 512 ? bhh[i] : 0.f);
}

// embedding gather, l-major: Mh2[l*1024+n][256]
__global__ __launch_bounds__(256) void k_embed(const float* __restrict__ emb, const int* __restrict__ lines,
                                               u16* __restrict__ Mh){
  int c = blockIdx.x * 256 + threadIdx.x;
  int row = c >> 5;
  int j = (c & 31) * 8;
  int ll = row >> 10, n = row & 1023;
  int line = lines[n * 64 + ll];
  const float* s = emb + line * 256 + j;
  bf16x8 v;
  #pragma unroll
  for (int q = 0; q < 8; q++) v[q] = (short)f2b(s[q]);
  *(bf16x8*)&Mh[row * 256 + j] = v;
}

// XA[t*N+n][0:64)=bf16(cond), [64:320)=Mh2[prev_action*1024+n]
__global__ __launch_bounds__(256) void k_xa(const float* __restrict__ cond, const u16* __restrict__ Mh2,
                                            const int* __restrict__ actions, u16* __restrict__ XA){
  int c = blockIdx.x * 256 + threadIdx.x;
  int tn = c / 40;
  int j = (c - tn * 40) * 8;
  bf16x8 v;
  if (j < 64){
    const float* s = cond + tn * 64 + j;
    #pragma unroll
    for (int q = 0; q < 8; q++) v[q] = (short)f2b(s[q]);
  } else {
    int t = tn >> 10, n = tn & 1023;
    int idx = t ? actions[(t - 1) * 1024 + n] : 0;   // p0 = one_hot(0)
    v = *(const bf16x8*)&Mh2[((size_t)idx * 1024 + n) * 256 + (j - 64)];
  }
  *(bf16x8*)&XA[tn * 320 + j] = v;
}

// ---------------- 128x128 NT GEMM, bf16 in/out, f32 acc ----------------
// MODE 0: plain. MODE 1: kT remap t*N+n -> n*128+t. MODE 2: scan-packed G.
template<int MODE, bool BIAS, bool RELU>
__global__ __launch_bounds__(256) void k_gemm(const u16* __restrict__ A, int lda,
                                              const u16* __restrict__ B, int ldb,
                                              const float* __restrict__ bias,
                                              u16* __restrict__ C, int ldc, int K){
  __shared__ __align__(16) u16 sA[4096], sB[4096];
  const int tid = threadIdx.x, wid = tid >> 6, l = tid & 63;
  const int l15 = l & 15, l4 = l >> 4;
  const int bxm = (MODE >= 2) ? blockIdx.y : blockIdx.x;
  const int bxn = (MODE >= 2) ? blockIdx.x : blockIdx.y;
  const int m0 = bxm * 128, n0 = bxn * 128;
  const int wm = (wid >> 1) * 64, wn = (wid & 1) * 64;
  const int srow = wid * 16 + (l >> 2), scol = (l & 3) * 8;
  f32x4 acc[4][4] = {};
  for (int k0 = 0; k0 < K; k0 += 32){
    gl_lds16(&A[(m0 + srow) * lda + k0 + scol],      (char*)sA + wid * 1024);
    gl_lds16(&A[(m0 + 64 + srow) * lda + k0 + scol], (char*)sA + 4096 + wid * 1024);
    gl_lds16(&B[(n0 + srow) * ldb + k0 + scol],      (char*)sB + wid * 1024);
    gl_lds16(&B[(n0 + 64 + srow) * ldb + k0 + scol], (char*)sB + 4096 + wid * 1024);
    __syncthreads();
    bf16x8 af[4], bfr[4];
    #pragma unroll
    for (int i = 0; i < 4; i++) af[i]  = *(const bf16x8*)&sA[(wm + i * 16 + l15) * 32 + l4 * 8];
    #pragma unroll
    for (int j = 0; j < 4; j++) bfr[j] = *(const bf16x8*)&sB[(wn + j * 16 + l15) * 32 + l4 * 8];
    #pragma unroll
    for (int i = 0; i < 4; i++)
      #pragma unroll
      for (int j = 0; j < 4; j++)
        acc[i][j] = mfma16(af[i], bfr[j], acc[i][j]);
    __syncthreads();
  }
  if constexpr (MODE >= 2){
    #pragma unroll
    for (int j = 0; j < 4; j++){
      int colp = wn + j * 16 + l15;
      float bia = BIAS ? bias[n0 + colp] : 0.f;
      size_t cpart = (size_t)blockIdx.x * 2048 + (size_t)(colp >> 4) * 256 + (size_t)(colp & 15) * 4;
      #pragma unroll
      for (int i = 0; i < 4; i++){
        int row = m0 + wm + i * 16 + l4 * 4;
        int t = row >> 10, n = row & 1023;
        size_t addr = ((size_t)t * 64 + (n >> 4)) * 12288 + (size_t)((n >> 2) & 3) * 64 + cpart;
        unsigned q0 = (unsigned)f2b(acc[i][j][0] + bia) | ((unsigned)f2b(acc[i][j][1] + bia) << 16);
        unsigned q1 = (unsigned)f2b(acc[i][j][2] + bia) | ((unsigned)f2b(acc[i][j][3] + bia) << 16);
        uint2 qq; qq.x = q0; qq.y = q1;
        *(uint2*)(C + addr) = qq;
      }
    }
  } else {
    #pragma unroll
    for (int i = 0; i < 4; i++)
      #pragma unroll
      for (int j = 0; j < 4; j++){
        int col = n0 + wn + j * 16 + l15;
        float bia = 0.f;
        if constexpr (BIAS) bia = bias[col];
        #pragma unroll
        for (int r = 0; r < 4; r++){
          int row = m0 + wm + i * 16 + l4 * 4 + r;
          float v = acc[i][j][r] + bia;
          if constexpr (RELU) v = fmaxf(v, 0.f);
          int orow = row;
          if constexpr (MODE == 1) orow = ((row & 1023) << 7) | (row >> 10);
          C[(size_t)orow * ldc + col] = f2b(v);
        }
      }
  }
}

// ---------------- GRU scans ----------------
// 8 waves x 64. Whh resident in VGPRs. Per step: 3 gl_lds stage (next gi),
// 1 coop ds_read_b128 + global_store_dwordx4 (prev h -> Ko), 8 ds_read_b128
// af (reused for all 6 accs), 48 MFMA, gate math, 8 ds_write_u16 hb.
// Sync: s_waitcnt lgkmcnt(0) vmcnt(1) + raw s_barrier — stores never drained.

template<bool CELL>
__global__ __launch_bounds__(512) void k_scan(
    const u16* __restrict__ Ga, const u16* __restrict__ Gbk,
    const u16* __restrict__ Wa, const u16* __restrict__ Wb,
    const float* __restrict__ bhha, const float* __restrict__ bhhb,
    u16* __restrict__ Ko)
{
  const int NSTEP = CELL ? 128 : 64;
  int dir = 0, nb = blockIdx.x;
  const u16 *G = Ga, *W = Wa; const float* bhh = bhha;
  if (!CELL){
    dir = blockIdx.x & 1; nb = blockIdx.x >> 1;
    if (dir){ G = Gbk; W = Wb; bhh = bhhb; }
  }
  const int n0 = nb * 16;
  __shared__ __align__(16) u16 hb[2][4096];
  __shared__ __align__(16) u16 gib[2][12288];
  const int tid = threadIdx.x, wid = tid >> 6, l = tid & 63;
  const int l15 = l & 15, l4 = l >> 4;
  for (int i = tid; i < 4096; i += 512) hb[0][i] = 0;
  const int col0 = wid * 16 + l15, col1 = col0 + 128;
  const float bhn0 = bhh[512 + col0], bhn1 = bhh[512 + col1];
  // resident weights
  bf16x8 w[3][2][8];
  #pragma unroll
  for (int g = 0; g < 3; g++)
    #pragma unroll
    for (int j = 0; j < 2; j++){
      const u16* wp = W + ((size_t)(g * 256 + (j ? col1 : col0)) * 256 + l4 * 8);
      #pragma unroll
      for (int kt = 0; kt < 8; kt++) w[g][j][kt] = *(const bf16x8*)&wp[kt * 32];
    }
  float h0[4] = {0.f,0.f,0.f,0.f}, h1[4] = {0.f,0.f,0.f,0.f};
  // cooperative output mapping: thread -> (row, phys chunk) -> logical col base
  const int orow = tid >> 5, oc8 = tid & 31;
  const int ocol = ((oc8 ^ (orow & 7)) << 3);
  {  // prologue: stage gi for first step
    int lc0 = (!CELL && dir) ? 63 : 0;
    const char* src = (const char*)(G + ((size_t)lc0 * 64 + nb) * 12288);
    #pragma unroll
    for (int q = 0; q < 3; q++)
      gl_lds16(src + (wid * 3 + q) * 1024 + l * 16, (char*)&gib[0][(wid * 3 + q) * 512]);
  }
  __syncthreads();
  int lc_prev = 0;
  #pragma unroll 1
  for (int s = 0; s < NSTEP; ++s){
    const int cb = s & 1;
    const int lc = CELL ? s : (dir ? 63 - s : s);
    const int sn = (s + 1 < NSTEP) ? s + 1 : s;
    const int lcn = CELL ? sn : (dir ? 63 - sn : sn);
    {  // stage next step's gi (3 vmem loads, issued FIRST)
      const char* src = (const char*)(G + ((size_t)lcn * 64 + nb) * 12288);
      #pragma unroll
      for (int q = 0; q < 3; q++)
        gl_lds16(src + (wid * 3 + q) * 1024 + l * 16, (char*)&gib[cb ^ 1][(wid * 3 + q) * 512]);
    }
    if (s > 0){  // cooperative store of previous step's h (complete in hb[cb])
      bf16x8 hv8 = *(const bf16x8*)&hb[cb][tid * 8];
      if (CELL){
        *(bf16x8*)&Ko[((size_t)lc_prev * 1024 + n0 + orow) * 256 + ocol] = hv8;
      } else {
        *(bf16x8*)&Ko[((size_t)(n0 + orow) * 64 + lc_prev) * 512 + dir * 256 + ocol] = hv8;
      }
    }
    // this step's gi
    bf16x4 y[6];
    #pragma unroll
    for (int yy = 0; yy < 6; yy++)
      y[yy] = *(const bf16x4*)&gib[cb][yy * 2048 + tid * 4];
    // A-fragments (read once, used for all 6 accumulators)
    bf16x8 af[8];
    #pragma unroll
    for (int kt = 0; kt < 8; kt++){
      int chunk = (kt * 4 + l4) ^ (l15 & 7);
      af[kt] = *(const bf16x8*)&hb[cb][l15 * 256 + chunk * 8];
    }
    f32x4 a00={0,0,0,0}, a10={0,0,0,0}, a20={0,0,0,0};
    f32x4 a01={0,0,0,0}, a11={0,0,0,0}, a21={0,0,0,0};
    #pragma unroll
    for (int kt = 0; kt < 8; kt++){
      a00 = mfma16(af[kt], w[0][0][kt], a00);
      a10 = mfma16(af[kt], w[1][0][kt], a10);
      a20 = mfma16(af[kt], w[2][0][kt], a20);
      a01 = mfma16(af[kt], w[0][1][kt], a01);
      a11 = mfma16(af[kt], w[1][1][kt], a11);
      a21 = mfma16(af[kt], w[2][1][kt], a21);
    }
    #pragma unroll
    for (int r = 0; r < 4; r++){
      int row = l4 * 4 + r;
      float rg = sigm(b2f((u16)y[0][r]) + a00[r]);
      float zg = sigm(b2f((u16)y[2][r]) + a10[r]);
      float nn = tanhf_(b2f((u16)y[4][r]) + rg * (a20[r] + bhn0));
      float hv = (1.f - zg) * nn + zg * h0[r];
      h0[r] = hv;
      hb[cb ^ 1][row * 256 + ((((col0 >> 3) ^ (row & 7)) << 3) | (col0 & 7))] = f2b(hv);
    }
    #pragma unroll
    for (int r = 0; r < 4; r++){
      int row = l4 * 4 + r;
      float rg = sigm(b2f((u16)y[1][r]) + a01[r]);
      float zg = sigm(b2f((u16)y[3][r]) + a11[r]);
      float nn = tanhf_(b2f((u16)y[5][r]) + rg * (a21[r] + bhn1));
      float hv = (1.f - zg) * nn + zg * h1[r];
      h1[r] = hv;
      hb[cb ^ 1][row * 256 + ((((col1 >> 3) ^ (row & 7)) << 3) | (col1 & 7))] = f2b(hv);
    }
    // sync: wait LDS writes + the 3 gl_lds (oldest vmem); leave store in flight
    __builtin_amdgcn_sched_barrier(0);
    asm volatile("s_waitcnt lgkmcnt(0) vmcnt(1)" ::: "memory");
    __builtin_amdgcn_sched_barrier(0);
    __builtin_amdgcn_s_barrier();
    __builtin_amdgcn_sched_barrier(0);
    lc_prev = lc;
  }
  {  // epilogue: last step's h is in hb[NSTEP&1]
    bf16x8 hv8 = *(const bf16x8*)&hb[NSTEP & 1][tid * 8];
    if (CELL){
      *(bf16x8*)&Ko[((size_t)lc_prev * 1024 + n0 + orow) * 256 + ocol] = hv8;
    } else {
      *(bf16x8*)&Ko[((size_t)(n0 + orow) * 64 + lc_prev) * 512 + dir * 256 + ocol] = hv8;
    }
  }
}

// ---------------- Hh (bf16) -> out h field (f32) ----------------

__global__ __launch_bounds__(256) void k_hout(const u16* __restrict__ Hh, float* __restrict__ out){
  int c = blockIdx.x * 256 + threadIdx.x;   // 131072*32 chunks of 8
  int ro = c >> 5, j = (c & 31) * 8;
  bf16x8 v = *(const bf16x8*)&Hh[(size_t)ro * 256 + j];
  float* o = out + (size_t)ro * 386 + 2 + j;
  #pragma unroll
  for (int q = 0; q < 4; q++){
    float2 f; f.x = b2f((u16)v[q * 2]); f.y = b2f((u16)v[q * 2 + 1]);
    *(float2*)(o + q * 2) = f;
  }
}

// ---------------- per-n logits GEMM (128x64, K=512) + row softmax ----------------

__global__ __launch_bounds__(256) void k_logits(const u16* __restrict__ Kc, const u16* __restrict__ kT,
                                                float* __restrict__ out){
  int n = blockIdx.x;
  const int tid = threadIdx.x, wid = tid >> 6, l = tid & 63, l15 = l & 15, l4 = l >> 4;
  const u16* An = kT + n * 65536;    // [128 t][512]
  const u16* Bn = Kc + n * 32768;    // [64 l][512]
  f32x4 acc[2][4] = {};
  for (int kt = 0; kt < 16; ++kt){
    bf16x8 a0 = *(const bf16x8*)&An[(wid * 32 + l15) * 512 + kt * 32 + l4 * 8];
    bf16x8 a1 = *(const bf16x8*)&An[(wid * 32 + 16 + l15) * 512 + kt * 32 + l4 * 8];
    #pragma unroll
    for (int j = 0; j < 4; j++){
      bf16x8 b = *(const bf16x8*)&Bn[(j * 16 + l15) * 512 + kt * 32 + l4 * 8];
      acc[0][j] = mfma16(a0, b, acc[0][j]);
      acc[1][j] = mfma16(a1, b, acc[1][j]);
    }
  }
  #pragma unroll
  for (int i = 0; i < 2; i++)
    #pragma unroll
    for (int r = 0; r < 4; r++){
      float v0 = acc[i][0][r], v1 = acc[i][1][r], v2 = acc[i][2][r], v3 = acc[i][3][r];
      float mx = fmaxf(fmaxf(v0, v1), fmaxf(v2, v3));
      #pragma unroll
      for (int s2 = 1; s2 < 16; s2 <<= 1) mx = fmaxf(mx, __shfl_xor(mx, s2));
      float e0 = __expf(v0 - mx), e1 = __expf(v1 - mx), e2 = __expf(v2 - mx), e3 = __expf(v3 - mx);
      float sm = e0 + e1 + e2 + e3;
      #pragma unroll
      for (int s2 = 1; s2 < 16; s2 <<= 1) sm += __shfl_xor(sm, s2);
      float rs = __builtin_amdgcn_rcpf(sm);
      int t = wid * 32 + i * 16 + l4 * 4 + r;
      float* o = out + (size_t)(t * 1024 + n) * 386 + 258;
      o[l15] = e0 * rs; o[16 + l15] = e1 * rs; o[32 + l15] = e2 * rs; o[48 + l15] = e3 * rs;
    }
}

// ---------------- a, v=critic(h), p=one_hot ----------------

__global__ __launch_bounds__(256) void k_pack(const int* __restrict__ actions,
                                              const float* __restrict__ cw, const float* __restrict__ cb,
                                              float* __restrict__ out){
  int idx = blockIdx.x * 4 + (threadIdx.x >> 6);
  int l = threadIdx.x & 63;
  float* o = out + (size_t)idx * 386;
  float s = 0.f;
  #pragma unroll
  for (int q = 0; q < 4; q++) s += o[2 + l + q * 64] * cw[l + q * 64];
  #pragma unroll
  for (int m = 32; m; m >>= 1) s += __shfl_down(s, m);
  int a = actions[idx];
  if (l == 0){ o[0] = (float)a; o[1] = s + cb[0]; }
  o[322 + l] = (l == a) ? 1.0f : 0.0f;
}

// ---------------- host ----------------

extern "C" void kernel_launch(void* const* d_in, const int* in_sizes, int n_in,
                              void* d_out, int out_size, void* d_ws, size_t ws_size,
                              hipStream_t stream){
  (void)in_sizes; (void)n_in; (void)out_size; (void)ws_size;
  const float* cond  = (const float*)d_in[0];
  const float* emb   = (const float*)d_in[1];
  const float* wih_f = (const float*)d_in[2];
  const float* whh_f = (const float*)d_in[3];
  const float* bih_f = (const float*)d_in[4];
  const float* bhh_f = (const float*)d_in[5];
  const float* wih_b = (const float*)d_in[6];
  const float* whh_b = (const float*)d_in[7];
  const float* bih_b = (const float*)d_in[8];
  const float* bhh_b = (const float*)d_in[9];
  const float* f_w0  = (const float*)d_in[10];
  const float* f_b0  = (const float*)d_in[11];
  const float* f_w1  = (const float*)d_in[12];
  const float* f_b1  = (const float*)d_in[13];
  const float* c_wih = (const float*)d_in[14];
  const float* c_whh = (const float*)d_in[15];
  const float* c_bih = (const float*)d_in[16];
  const float* c_bhh = (const float*)d_in[17];
  const float* actw  = (const float*)d_in[18];
  const float* actb  = (const float*)d_in[19];
  const float* cw    = (const float*)d_in[20];
  const float* cbi   = (const float*)d_in[21];
  const int* lines   = (const int*)d_in[22];
  const int* actions = (const int*)d_in[23];
  float* out = (float*)d_out;

  char* ws = (char*)d_ws;
  size_t off = 0;
  auto alloc = [&](size_t b){ char* p = ws + off; off += (b + 255) & ~(size_t)255; return p; };
  u16* Kc  = (u16*)alloc((size_t)1024 * 64 * 512 * 2);   // 64 MiB
  char* RA = alloc((size_t)128 * 1024 * 768 * 2);        // 192 MiB: Gf|Gb -> GI -> kT
  char* RD = alloc((size_t)128 * 1024 * 320 * 2);        // 80 MiB:  XA -> X -> Hh
  u16* X0  = (u16*)alloc((size_t)128 * 1024 * 256 * 2);  // 64 MiB (Mh2 early, then MLP mid)
  u16* wihf_h = (u16*)alloc(196608 * 2);
  u16* whhf_h = (u16*)alloc(196608 * 2);
  u16* wihb_h = (u16*)alloc(196608 * 2);
  u16* whhb_h = (u16*)alloc(196608 * 2);
  u16* cwih_h = (u16*)alloc(196608 * 2);
  u16* cwhh_h = (u16*)alloc(196608 * 2);
  u16* fw0_h  = (u16*)alloc(81920 * 2);
  u16* fw1_h  = (u16*)alloc(65536 * 2);
  u16* actw_h = (u16*)alloc(131072 * 2);
  float* bc_f = (float*)alloc(768 * 4);
  float* bc_b = (float*)alloc(768 * 4);
  float* bc_c = (float*)alloc(768 * 4);

  u16* Gf  = (u16*)RA;                                   // packed [l][nb][...] 96 MiB
  u16* Gb  = (u16*)(RA + (size_t)64 * 1024 * 768 * 2);
  u16* GI  = (u16*)RA;                                   // packed [t][nb][...] 192 MiB
  u16* kT  = (u16*)RA;
  u16* XA  = (u16*)RD;
  u16* X   = (u16*)RD;
  u16* Hh  = (u16*)RD;
  u16* Mh2 = X0;                                          // l-major embeddings

  // 1. weights -> bf16
  const float* srcs[9] = {wih_f, whh_f, wih_b, whh_b, c_wih, c_whh, f_w0, f_w1, actw};
  u16* dsts[9] = {wihf_h, whhf_h, wihb_h, whhb_h, cwih_h, cwhh_h, fw0_h, fw1_h, actw_h};
  const int ns[9] = {196608,196608,196608,196608,196608,196608,81920,65536,131072};
  for (int i = 0; i < 9; i++)
    k_f2b<<<dim3((ns[i] + 255) / 256), dim3(256), 0, stream>>>(srcs[i], dsts[i], ns[i]);
  // 2. combined biases
  k_bias<<<dim3(3), dim3(256), 0, stream>>>(bih_f, bhh_f, bc_f);
  k_bias<<<dim3(3), dim3(256), 0, stream>>>(bih_b, bhh_b, bc_b);
  k_bias<<<dim3(3), dim3(256), 0, stream>>>(c_bih, c_bhh, bc_c);
  // 3. embedding gather (l-major only)
  k_embed<<<dim3(8192), dim3(256), 0, stream>>>(emb, lines, Mh2);
  // 4/5. line-GRU input projections -> packed Gf/Gb (bias folded)
  k_gemm<2,true,false><<<dim3(6,512), dim3(256), 0, stream>>>(Mh2, 256, wihf_h, 256, bc_f, Gf, 0, 256);
  k_gemm<2,true,false><<<dim3(6,512), dim3(256), 0, stream>>>(Mh2, 256, wihb_h, 256, bc_b, Gb, 0, 256);
  // 6. bidirectional line-GRU scan -> Kc
  k_scan<false><<<dim3(128), dim3(512), 0, stream>>>(Gf, Gb, whhf_h, whhb_h, bhh_f, bhh_b, Kc);
  // 7. pointer-read gather + cond concat
  k_xa<<<dim3(20480), dim3(256), 0, stream>>>(cond, Mh2, actions, XA);
  // 8/9. MLP
  k_gemm<0,true,true><<<dim3(1024,2), dim3(256), 0, stream>>>(XA, 320, fw0_h, 320, f_b0, X0, 256, 320);
  k_gemm<0,true,true><<<dim3(1024,2), dim3(256), 0, stream>>>(X0, 256, fw1_h, 256, f_b1, X, 256, 256);
  // 10. GRUCell input projections -> packed GI (bias folded)
  k_gemm<2,true,false><<<dim3(6,1024), dim3(256), 0, stream>>>(X, 256, cwih_h, 256, bc_c, GI, 0, 256);
  // 11. GRUCell scan over T -> Hh bf16
  k_scan<true><<<dim3(64), dim3(512), 0, stream>>>(GI, nullptr, cwhh_h, nullptr, c_bhh, nullptr, Hh);
  // 12. expand Hh -> out h field (f32)
  k_hout<<<dim3(16384), dim3(256), 0, stream>>>(Hh, out);
  // 13. actor: kT = [n][t][512]
  k_gemm<1,true,false><<<dim3(1024,4), dim3(256), 0, stream>>>(Hh, 256, actw_h, 256, actb, kT, 512, 256);
  // 14. logits + softmax
  k_logits<<<dim3(1024), dim3(256), 0, stream>>>(Kc, kT, out);
  // 15. a, v, one_hot(p)
  k_pack<<<dim3(32768), dim3(256), 0, stream>>>(actions, cw, cbi, out);
  // 16. second output = hx[-1:]
  hipMemcpyAsync(out + (size_t)128 * 1024 * 386, out + (size_t)127 * 1024 * 386,
                 (size_t)1024 * 386 * 4, hipMemcpyDeviceToDevice, stream);
}

// Round 6
// 1273.769 us; speedup vs baseline: 3.1464x; 1.0635x over previous
//
#include <hip/hip_runtime.h>

// T=128, N=1024, H=256, L=64, C=64, V=1000.
// R6: scans moved to fp8-e4m3 resident weights. R5 post-mortem: VGPR_Count=128
// proved Whh (192 VGPRs bf16) was never register-resident — compiler re-streamed
// 384 KB/block/step from L2. fp8 halves weights to 96 VGPR + af 16 -> ~190 live
// regs, fits the 256-reg cap from __launch_bounds__(512,2). h master stays f32;
// only the recurrent matvec runs fp8. Also fixed s==0 vmcnt race.

typedef unsigned short u16;
typedef __attribute__((ext_vector_type(8))) short bf16x8;   // 8 bf16 = 4 VGPR
typedef __attribute__((ext_vector_type(4))) short bf16x4;   // 4 bf16 = 2 VGPR
typedef __attribute__((ext_vector_type(4))) float f32x4;
typedef __attribute__((ext_vector_type(2))) unsigned int u32x2;  // 8 fp8 = 2 VGPR

#define DEVFN static __device__ __forceinline__

DEVFN float b2f(u16 h){ union{unsigned u; float f;} v; v.u = ((unsigned)h) << 16; return v.f; }
DEVFN u16 f2b(float f){ union{float f; unsigned u;} v; v.f = f;
  return (u16)((v.u + 0x7fffu + ((v.u >> 16) & 1u)) >> 16); }

// f32 -> fp8 e4m3fn, full (denorm-correct, RN-ish) — for weights (|w|<=0.0625,
// 25% of them live in the denorm range 2^-9..2^-6).
DEVFN unsigned f2e4m3_full(float f){
  union{float ff; unsigned u;} v; v.ff = f;
  unsigned s = (v.u >> 31) << 7;
  int e = (int)((v.u >> 23) & 0xff) - 127;
  if (e < -10) return s;
  unsigned m = (v.u & 0x7fffff) | 0x800000;
  if (e < -6){
    int sh = 20 + (-6 - e);                   // 21..24
    unsigned q = (m + (1u << (sh - 1))) >> sh;
    return s | q;                             // q<=8; 8 == 2^-6 normal encoding
  }
  unsigned q = ((unsigned)(e + 7) << 3) | ((m & 0x7fffff) >> 20);
  q += (m >> 19) & 1u;
  if (q > 0x7e) q = 0x7e;
  return s | q;
}
// fast path for h (|h|<=1): flush below 2^-6 (error <=0.016, negligible in matvec)
DEVFN unsigned f2e4m3(float f){
  union{float ff; unsigned u;} v; v.ff = f;
  unsigned s = (v.u >> 31) << 7;
  int e = (int)((v.u >> 23) & 0xff) - 127;
  if (e < -6) return s;
  unsigned q = ((unsigned)(e + 7) << 3) | ((v.u & 0x7fffff) >> 20);
  q += (v.u >> 19) & 1u;
  if (q > 0x7e) q = 0x7e;
  return s | q;
}

DEVFN f32x4 mfma16(bf16x8 a, bf16x8 b, f32x4 c){
  asm("v_mfma_f32_16x16x32_bf16 %0, %1, %2, %0" : "+v"(c) : "v"(a), "v"(b));
  return c;
}
DEVFN f32x4 mfma8(u32x2 a, u32x2 b, f32x4 c){
  asm("v_mfma_f32_16x16x32_fp8_fp8 %0, %1, %2, %0" : "+v"(c) : "v"(a), "v"(b));
  return c;
}
DEVFN void gl_lds16(const void* g, void* l){
  __builtin_amdgcn_global_load_lds((const __attribute__((address_space(1))) void*)g,
                                   (__attribute__((address_space(3))) void*)l, 16, 0, 0);
}
DEVFN float sigm(float x){ return __builtin_amdgcn_rcpf(1.0f + __expf(-x)); }
DEVFN float tanhf_(float x){ float e = __expf(2.0f * x); return 1.0f - 2.0f * __builtin_amdgcn_rcpf(e + 1.0f); }

// ---------------- small converters / prep ----------------

__global__ __launch_bounds__(256) void k_f2b(const float* __restrict__ s, u16* __restrict__ d, int n){
  int i = blockIdx.x * 256 + threadIdx.x;
  if (i < n) d[i] = f2b(s[i]);
}

__global__ __launch_bounds__(256) void k_w8(const float* __restrict__ s, unsigned char* __restrict__ d, int n){
  int i = blockIdx.x * 256 + threadIdx.x;
  if (i < n) d[i] = (unsigned char)f2e4m3_full(s[i]);
}

__global__ __launch_bounds__(256) void k_bias(const float* __restrict__ bih, const float* __restrict__ bhh,
                                              float* __restrict__ dst){
  int i = blockIdx.x * 256 + threadIdx.x;
  if (i < 768) dst[i] = bih[i] + (i < 512 ? bhh[i] : 0.f);
}

// embedding gather, l-major: Mh2[l*1024+n][256]
__global__ __launch_bounds__(256) void k_embed(const float* __restrict__ emb, const int* __restrict__ lines,
                                               u16* __restrict__ Mh){
  int c = blockIdx.x * 256 + threadIdx.x;
  int row = c >> 5;
  int j = (c & 31) * 8;
  int ll = row >> 10, n = row & 1023;
  int line = lines[n * 64 + ll];
  const float* s = emb + line * 256 + j;
  bf16x8 v;
  #pragma unroll
  for (int q = 0; q < 8; q++) v[q] = (short)f2b(s[q]);
  *(bf16x8*)&Mh[row * 256 + j] = v;
}

// XA[t*N+n][0:64)=bf16(cond), [64:320)=Mh2[prev_action*1024+n]
__global__ __launch_bounds__(256) void k_xa(const float* __restrict__ cond, const u16* __restrict__ Mh2,
                                            const int* __restrict__ actions, u16* __restrict__ XA){
  int c = blockIdx.x * 256 + threadIdx.x;
  int tn = c / 40;
  int j = (c - tn * 40) * 8;
  bf16x8 v;
  if (j < 64){
    const float* s = cond + tn * 64 + j;
    #pragma unroll
    for (int q = 0; q < 8; q++) v[q] = (short)f2b(s[q]);
  } else {
    int t = tn >> 10, n = tn & 1023;
    int idx = t ? actions[(t - 1) * 1024 + n] : 0;   // p0 = one_hot(0)
    v = *(const bf16x8*)&Mh2[((size_t)idx * 1024 + n) * 256 + (j - 64)];
  }
  *(bf16x8*)&XA[tn * 320 + j] = v;
}

// ---------------- 128x128 NT GEMM, bf16 in/out, f32 acc ----------------
// MODE 0: plain. MODE 1: kT remap t*N+n -> n*128+t. MODE 2: scan-packed G.
template<int MODE, bool BIAS, bool RELU>
__global__ __launch_bounds__(256) void k_gemm(const u16* __restrict__ A, int lda,
                                              const u16* __restrict__ B, int ldb,
                                              const float* __restrict__ bias,
                                              u16* __restrict__ C, int ldc, int K){
  __shared__ __align__(16) u16 sA[4096], sB[4096];
  const int tid = threadIdx.x, wid = tid >> 6, l = tid & 63;
  const int l15 = l & 15, l4 = l >> 4;
  const int bxm = (MODE >= 2) ? blockIdx.y : blockIdx.x;
  const int bxn = (MODE >= 2) ? blockIdx.x : blockIdx.y;
  const int m0 = bxm * 128, n0 = bxn * 128;
  const int wm = (wid >> 1) * 64, wn = (wid & 1) * 64;
  const int srow = wid * 16 + (l >> 2), scol = (l & 3) * 8;
  f32x4 acc[4][4] = {};
  for (int k0 = 0; k0 < K; k0 += 32){
    gl_lds16(&A[(m0 + srow) * lda + k0 + scol],      (char*)sA + wid * 1024);
    gl_lds16(&A[(m0 + 64 + srow) * lda + k0 + scol], (char*)sA + 4096 + wid * 1024);
    gl_lds16(&B[(n0 + srow) * ldb + k0 + scol],      (char*)sB + wid * 1024);
    gl_lds16(&B[(n0 + 64 + srow) * ldb + k0 + scol], (char*)sB + 4096 + wid * 1024);
    __syncthreads();
    bf16x8 af[4], bfr[4];
    #pragma unroll
    for (int i = 0; i < 4; i++) af[i]  = *(const bf16x8*)&sA[(wm + i * 16 + l15) * 32 + l4 * 8];
    #pragma unroll
    for (int j = 0; j < 4; j++) bfr[j] = *(const bf16x8*)&sB[(wn + j * 16 + l15) * 32 + l4 * 8];
    #pragma unroll
    for (int i = 0; i < 4; i++)
      #pragma unroll
      for (int j = 0; j < 4; j++)
        acc[i][j] = mfma16(af[i], bfr[j], acc[i][j]);
    __syncthreads();
  }
  if constexpr (MODE >= 2){
    #pragma unroll
    for (int j = 0; j < 4; j++){
      int colp = wn + j * 16 + l15;
      float bia = BIAS ? bias[n0 + colp] : 0.f;
      size_t cpart = (size_t)blockIdx.x * 2048 + (size_t)(colp >> 4) * 256 + (size_t)(colp & 15) * 4;
      #pragma unroll
      for (int i = 0; i < 4; i++){
        int row = m0 + wm + i * 16 + l4 * 4;
        int t = row >> 10, n = row & 1023;
        size_t addr = ((size_t)t * 64 + (n >> 4)) * 12288 + (size_t)((n >> 2) & 3) * 64 + cpart;
        unsigned q0 = (unsigned)f2b(acc[i][j][0] + bia) | ((unsigned)f2b(acc[i][j][1] + bia) << 16);
        unsigned q1 = (unsigned)f2b(acc[i][j][2] + bia) | ((unsigned)f2b(acc[i][j][3] + bia) << 16);
        uint2 qq; qq.x = q0; qq.y = q1;
        *(uint2*)(C + addr) = qq;
      }
    }
  } else {
    #pragma unroll
    for (int i = 0; i < 4; i++)
      #pragma unroll
      for (int j = 0; j < 4; j++){
        int col = n0 + wn + j * 16 + l15;
        float bia = 0.f;
        if constexpr (BIAS) bia = bias[col];
        #pragma unroll
        for (int r = 0; r < 4; r++){
          int row = m0 + wm + i * 16 + l4 * 4 + r;
          float v = acc[i][j][r] + bia;
          if constexpr (RELU) v = fmaxf(v, 0.f);
          int orow = row;
          if constexpr (MODE == 1) orow = ((row & 1023) << 7) | (row >> 10);
          C[(size_t)orow * ldc + col] = f2b(v);
        }
      }
  }
}

// ---------------- GRU scans (fp8 recurrent matvec) ----------------
// 8 waves x 64, __launch_bounds__(512,2) -> 256-reg cap. Whh resident as fp8
// (w8: 96 VGPR). h master f32 in regs; hb8 fp8 copy (8B-chunk XOR swizzle) for
// MFMA A; hbf bf16 copy for coop Ko store. Per step: 3 gl_lds (next gi),
// 1 coop store, 8 ds_read_b64 af, 48 fp8 MFMA, gates, 8+8 LDS writes.
// Sync: counted vmcnt (vmcnt(0) at s==0 — fixes R5 handoff race) + s_barrier.

template<bool CELL>
__global__ __launch_bounds__(512, 2) void k_scan(
    const u16* __restrict__ Ga, const u16* __restrict__ Gbk,
    const unsigned char* __restrict__ Wa, const unsigned char* __restrict__ Wb,
    const float* __restrict__ bhha, const float* __restrict__ bhhb,
    u16* __restrict__ Ko)
{
  const int NSTEP = CELL ? 128 : 64;
  int dir = 0, nb = blockIdx.x;
  const u16 *G = Ga; const unsigned char* W = Wa; const float* bhh = bhha;
  if (!CELL){
    dir = blockIdx.x & 1; nb = blockIdx.x >> 1;
    if (dir){ G = Gbk; W = Wb; bhh = bhhb; }
  }
  const int n0 = nb * 16;
  __shared__ __align__(16) u16 hbf[2][4096];
  __shared__ __align__(16) unsigned char hb8[2][4096];
  __shared__ __align__(16) u16 gib[2][12288];
  const int tid = threadIdx.x, wid = tid >> 6, l = tid & 63;
  const int l15 = l & 15, l4 = l >> 4;
  for (int i = tid; i < 4096; i += 512){ hbf[0][i] = 0; hb8[0][i] = 0; }
  const int col0 = wid * 16 + l15, col1 = col0 + 128;
  const float bhn0 = bhh[512 + col0], bhn1 = bhh[512 + col1];
  // resident fp8 weights: per (gate, j, kt): B-frag = 8 fp8 at W[cc*256 + kt*32 + l4*8]
  u32x2 w8[3][2][8];
  #pragma unroll
  for (int g = 0; g < 3; g++)
    #pragma unroll
    for (int j = 0; j < 2; j++){
      const unsigned char* wp = W + ((size_t)(g * 256 + (j ? col1 : col0)) * 256 + l4 * 8);
      #pragma unroll
      for (int kt = 0; kt < 8; kt++) w8[g][j][kt] = *(const u32x2*)&wp[kt * 32];
    }
  float h0[4] = {0.f,0.f,0.f,0.f}, h1[4] = {0.f,0.f,0.f,0.f};
  // cooperative output mapping: thread -> (row, phys 16B chunk) -> logical col
  const int orow = tid >> 5, oc8 = tid & 31;
  const int ocol = ((oc8 ^ (orow & 7)) << 3);
  {  // prologue: stage gi for first step
    int lc0 = (!CELL && dir) ? 63 : 0;
    const char* src = (const char*)(G + ((size_t)lc0 * 64 + nb) * 12288);
    #pragma unroll
    for (int q = 0; q < 3; q++)
      gl_lds16(src + (wid * 3 + q) * 1024 + l * 16, (char*)&gib[0][(wid * 3 + q) * 512]);
  }
  __syncthreads();
  int lc_prev = 0;
  #pragma unroll 1
  for (int s = 0; s < NSTEP; ++s){
    const int cb = s & 1;
    const int lc = CELL ? s : (dir ? 63 - s : s);
    const int sn = (s + 1 < NSTEP) ? s + 1 : s;
    const int lcn = CELL ? sn : (dir ? 63 - sn : sn);
    {  // stage next step's gi (3 vmem loads, issued FIRST)
      const char* src = (const char*)(G + ((size_t)lcn * 64 + nb) * 12288);
      #pragma unroll
      for (int q = 0; q < 3; q++)
        gl_lds16(src + (wid * 3 + q) * 1024 + l * 16, (char*)&gib[cb ^ 1][(wid * 3 + q) * 512]);
    }
    if (s > 0){  // cooperative store of previous step's h
      bf16x8 hv8 = *(const bf16x8*)&hbf[cb][tid * 8];
      if (CELL){
        *(bf16x8*)&Ko[((size_t)lc_prev * 1024 + n0 + orow) * 256 + ocol] = hv8;
      } else {
        *(bf16x8*)&Ko[((size_t)(n0 + orow) * 64 + lc_prev) * 512 + dir * 256 + ocol] = hv8;
      }
    }
    // A-fragments: fp8 h rows, 8B-chunk XOR swizzle
    u32x2 af8[8];
    #pragma unroll
    for (int kt = 0; kt < 8; kt++){
      int chunk = (kt * 4 + l4) ^ (l15 & 7);
      af8[kt] = *(const u32x2*)&hb8[cb][l15 * 256 + chunk * 8];
    }
    f32x4 a00={0,0,0,0}, a10={0,0,0,0}, a20={0,0,0,0};
    f32x4 a01={0,0,0,0}, a11={0,0,0,0}, a21={0,0,0,0};
    #pragma unroll
    for (int kt = 0; kt < 8; kt++){
      a00 = mfma8(af8[kt], w8[0][0][kt], a00);
      a10 = mfma8(af8[kt], w8[1][0][kt], a10);
      a20 = mfma8(af8[kt], w8[2][0][kt], a20);
      a01 = mfma8(af8[kt], w8[0][1][kt], a01);
      a11 = mfma8(af8[kt], w8[1][1][kt], a11);
      a21 = mfma8(af8[kt], w8[2][1][kt], a21);
    }
    // this step's gi
    bf16x4 y[6];
    #pragma unroll
    for (int yy = 0; yy < 6; yy++)
      y[yy] = *(const bf16x4*)&gib[cb][yy * 2048 + tid * 4];
    #pragma unroll
    for (int r = 0; r < 4; r++){
      int row = l4 * 4 + r;
      float rg = sigm(b2f((u16)y[0][r]) + a00[r]);
      float zg = sigm(b2f((u16)y[2][r]) + a10[r]);
      float nn = tanhf_(b2f((u16)y[4][r]) + rg * (a20[r] + bhn0));
      float hv = (1.f - zg) * nn + zg * h0[r];
      h0[r] = hv;
      hbf[cb ^ 1][row * 256 + ((((col0 >> 3) ^ (row & 7)) << 3) | (col0 & 7))] = f2b(hv);
      hb8[cb ^ 1][row * 256 + ((((col0 >> 3) ^ (row & 7)) << 3) | (col0 & 7))] = (unsigned char)f2e4m3(hv);
    }
    #pragma unroll
    for (int r = 0; r < 4; r++){
      int row = l4 * 4 + r;
      float rg = sigm(b2f((u16)y[1][r]) + a01[r]);
      float zg = sigm(b2f((u16)y[3][r]) + a11[r]);
      float nn = tanhf_(b2f((u16)y[5][r]) + rg * (a21[r] + bhn1));
      float hv = (1.f - zg) * nn + zg * h1[r];
      h1[r] = hv;
      hbf[cb ^ 1][row * 256 + ((((col1 >> 3) ^ (row & 7)) << 3) | (col1 & 7))] = f2b(hv);
      hb8[cb ^ 1][row * 256 + ((((col1 >> 3) ^ (row & 7)) << 3) | (col1 & 7))] = (unsigned char)f2e4m3(hv);
    }
    // sync: wait LDS + the 3 gl_lds; leave the store in flight (s>0)
    __builtin_amdgcn_sched_barrier(0);
    if (s == 0) asm volatile("s_waitcnt lgkmcnt(0) vmcnt(0)" ::: "memory");
    else        asm volatile("s_waitcnt lgkmcnt(0) vmcnt(1)" ::: "memory");
    __builtin_amdgcn_sched_barrier(0);
    __builtin_amdgcn_s_barrier();
    __builtin_amdgcn_sched_barrier(0);
    lc_prev = lc;
  }
  {  // epilogue: last step's h is in hbf[NSTEP&1]
    bf16x8 hv8 = *(const bf16x8*)&hbf[NSTEP & 1][tid * 8];
    if (CELL){
      *(bf16x8*)&Ko[((size_t)lc_prev * 1024 + n0 + orow) * 256 + ocol] = hv8;
    } else {
      *(bf16x8*)&Ko[((size_t)(n0 + orow) * 64 + lc_prev) * 512 + dir * 256 + ocol] = hv8;
    }
  }
}

// ---------------- Hh (bf16) -> out h field (f32) ----------------

__global__ __launch_bounds__(256) void k_hout(const u16* __restrict__ Hh, float* __restrict__ out){
  int c = blockIdx.x * 256 + threadIdx.x;
  int ro = c >> 5, j = (c & 31) * 8;
  bf16x8 v = *(const bf16x8*)&Hh[(size_t)ro * 256 + j];
  float* o = out + (size_t)ro * 386 + 2 + j;
  #pragma unroll
  for (int q = 0; q < 4; q++){
    float2 f; f.x = b2f((u16)v[q * 2]); f.y = b2f((u16)v[q * 2 + 1]);
    *(float2*)(o + q * 2) = f;
  }
}

// ---------------- per-n logits GEMM (128x64, K=512) + row softmax ----------------

__global__ __launch_bounds__(256) void k_logits(const u16* __restrict__ Kc, const u16* __restrict__ kT,
                                                float* __restrict__ out){
  int n = blockIdx.x;
  const int tid = threadIdx.x, wid = tid >> 6, l = tid & 63, l15 = l & 15, l4 = l >> 4;
  const u16* An = kT + n * 65536;    // [128 t][512]
  const u16* Bn = Kc + n * 32768;    // [64 l][512]
  f32x4 acc[2][4] = {};
  for (int kt = 0; kt < 16; ++kt){
    bf16x8 a0 = *(const bf16x8*)&An[(wid * 32 + l15) * 512 + kt * 32 + l4 * 8];
    bf16x8 a1 = *(const bf16x8*)&An[(wid * 32 + 16 + l15) * 512 + kt * 32 + l4 * 8];
    #pragma unroll
    for (int j = 0; j < 4; j++){
      bf16x8 b = *(const bf16x8*)&Bn[(j * 16 + l15) * 512 + kt * 32 + l4 * 8];
      acc[0][j] = mfma16(a0, b, acc[0][j]);
      acc[1][j] = mfma16(a1, b, acc[1][j]);
    }
  }
  #pragma unroll
  for (int i = 0; i < 2; i++)
    #pragma unroll
    for (int r = 0; r < 4; r++){
      float v0 = acc[i][0][r], v1 = acc[i][1][r], v2 = acc[i][2][r], v3 = acc[i][3][r];
      float mx = fmaxf(fmaxf(v0, v1), fmaxf(v2, v3));
      #pragma unroll
      for (int s2 = 1; s2 < 16; s2 <<= 1) mx = fmaxf(mx, __shfl_xor(mx, s2));
      float e0 = __expf(v0 - mx), e1 = __expf(v1 - mx), e2 = __expf(v2 - mx), e3 = __expf(v3 - mx);
      float sm = e0 + e1 + e2 + e3;
      #pragma unroll
      for (int s2 = 1; s2 < 16; s2 <<= 1) sm += __shfl_xor(sm, s2);
      float rs = __builtin_amdgcn_rcpf(sm);
      int t = wid * 32 + i * 16 + l4 * 4 + r;
      float* o = out + (size_t)(t * 1024 + n) * 386 + 258;
      o[l15] = e0 * rs; o[16 + l15] = e1 * rs; o[32 + l15] = e2 * rs; o[48 + l15] = e3 * rs;
    }
}

// ---------------- a, v=critic(h), p=one_hot ----------------

__global__ __launch_bounds__(256) void k_pack(const int* __restrict__ actions,
                                              const float* __restrict__ cw, const float* __restrict__ cb,
                                              float* __restrict__ out){
  int idx = blockIdx.x * 4 + (threadIdx.x >> 6);
  int l = threadIdx.x & 63;
  float* o = out + (size_t)idx * 386;
  float s = 0.f;
  #pragma unroll
  for (int q = 0; q < 4; q++) s += o[2 + l + q * 64] * cw[l + q * 64];
  #pragma unroll
  for (int m = 32; m; m >>= 1) s += __shfl_down(s, m);
  int a = actions[idx];
  if (l == 0){ o[0] = (float)a; o[1] = s + cb[0]; }
  o[322 + l] = (l == a) ? 1.0f : 0.0f;
}

// ---------------- host ----------------

extern "C" void kernel_launch(void* const* d_in, const int* in_sizes, int n_in,
                              void* d_out, int out_size, void* d_ws, size_t ws_size,
                              hipStream_t stream){
  (void)in_sizes; (void)n_in; (void)out_size; (void)ws_size;
  const float* cond  = (const float*)d_in[0];
  const float* emb   = (const float*)d_in[1];
  const float* wih_f = (const float*)d_in[2];
  const float* whh_f = (const float*)d_in[3];
  const float* bih_f = (const float*)d_in[4];
  const float* bhh_f = (const float*)d_in[5];
  const float* wih_b = (const float*)d_in[6];
  const float* whh_b = (const float*)d_in[7];
  const float* bih_b = (const float*)d_in[8];
  const float* bhh_b = (const float*)d_in[9];
  const float* f_w0  = (const float*)d_in[10];
  const float* f_b0  = (const float*)d_in[11];
  const float* f_w1  = (const float*)d_in[12];
  const float* f_b1  = (const float*)d_in[13];
  const float* c_wih = (const float*)d_in[14];
  const float* c_whh = (const float*)d_in[15];
  const float* c_bih = (const float*)d_in[16];
  const float* c_bhh = (const float*)d_in[17];
  const float* actw  = (const float*)d_in[18];
  const float* actb  = (const float*)d_in[19];
  const float* cw    = (const float*)d_in[20];
  const float* cbi   = (const float*)d_in[21];
  const int* lines   = (const int*)d_in[22];
  const int* actions = (const int*)d_in[23];
  float* out = (float*)d_out;

  char* ws = (char*)d_ws;
  size_t off = 0;
  auto alloc = [&](size_t b){ char* p = ws + off; off += (b + 255) & ~(size_t)255; return p; };
  u16* Kc  = (u16*)alloc((size_t)1024 * 64 * 512 * 2);   // 64 MiB
  char* RA = alloc((size_t)128 * 1024 * 768 * 2);        // 192 MiB: Gf|Gb -> GI -> kT
  char* RD = alloc((size_t)128 * 1024 * 320 * 2);        // 80 MiB:  XA -> X -> Hh
  u16* X0  = (u16*)alloc((size_t)128 * 1024 * 256 * 2);  // 64 MiB (Mh2 early, then MLP mid)
  u16* wihf_h = (u16*)alloc(196608 * 2);
  u16* wihb_h = (u16*)alloc(196608 * 2);
  u16* cwih_h = (u16*)alloc(196608 * 2);
  u16* fw0_h  = (u16*)alloc(81920 * 2);
  u16* fw1_h  = (u16*)alloc(65536 * 2);
  u16* actw_h = (u16*)alloc(131072 * 2);
  unsigned char* w8f = (unsigned char*)alloc(196608);
  unsigned char* w8b = (unsigned char*)alloc(196608);
  unsigned char* w8c = (unsigned char*)alloc(196608);
  float* bc_f = (float*)alloc(768 * 4);
  float* bc_b = (float*)alloc(768 * 4);
  float* bc_c = (float*)alloc(768 * 4);

  u16* Gf  = (u16*)RA;                                   // packed [l][nb][...] 96 MiB
  u16* Gb  = (u16*)(RA + (size_t)64 * 1024 * 768 * 2);
  u16* GI  = (u16*)RA;                                   // packed [t][nb][...] 192 MiB
  u16* kT  = (u16*)RA;
  u16* XA  = (u16*)RD;
  u16* X   = (u16*)RD;
  u16* Hh  = (u16*)RD;
  u16* Mh2 = X0;                                          // l-major embeddings

  // 1. GEMM weights -> bf16; recurrent weights -> fp8 e4m3
  const float* srcs[6] = {wih_f, wih_b, c_wih, f_w0, f_w1, actw};
  u16* dsts[6] = {wihf_h, wihb_h, cwih_h, fw0_h, fw1_h, actw_h};
  const int ns[6] = {196608,196608,196608,81920,65536,131072};
  for (int i = 0; i < 6; i++)
    k_f2b<<<dim3((ns[i] + 255) / 256), dim3(256), 0, stream>>>(srcs[i], dsts[i], ns[i]);
  k_w8<<<dim3(768), dim3(256), 0, stream>>>(whh_f, w8f, 196608);
  k_w8<<<dim3(768), dim3(256), 0, stream>>>(whh_b, w8b, 196608);
  k_w8<<<dim3(768), dim3(256), 0, stream>>>(c_whh, w8c, 196608);
  // 2. combined biases
  k_bias<<<dim3(3), dim3(256), 0, stream>>>(bih_f, bhh_f, bc_f);
  k_bias<<<dim3(3), dim3(256), 0, stream>>>(bih_b, bhh_b, bc_b);
  k_bias<<<dim3(3), dim3(256), 0, stream>>>(c_bih, c_bhh, bc_c);
  // 3. embedding gather (l-major)
  k_embed<<<dim3(8192), dim3(256), 0, stream>>>(emb, lines, Mh2);
  // 4/5. line-GRU input projections -> packed Gf/Gb (bias folded)
  k_gemm<2,true,false><<<dim3(6,512), dim3(256), 0, stream>>>(Mh2, 256, wihf_h, 256, bc_f, Gf, 0, 256);
  k_gemm<2,true,false><<<dim3(6,512), dim3(256), 0, stream>>>(Mh2, 256, wihb_h, 256, bc_b, Gb, 0, 256);
  // 6. bidirectional line-GRU scan -> Kc
  k_scan<false><<<dim3(128), dim3(512), 0, stream>>>(Gf, Gb, w8f, w8b, bhh_f, bhh_b, Kc);
  // 7. pointer-read gather + cond concat
  k_xa<<<dim3(20480), dim3(256), 0, stream>>>(cond, Mh2, actions, XA);
  // 8/9. MLP
  k_gemm<0,true,true><<<dim3(1024,2), dim3(256), 0, stream>>>(XA, 320, fw0_h, 320, f_b0, X0, 256, 320);
  k_gemm<0,true,true><<<dim3(1024,2), dim3(256), 0, stream>>>(X0, 256, fw1_h, 256, f_b1, X, 256, 256);
  // 10. GRUCell input projections -> packed GI (bias folded)
  k_gemm<2,true,false><<<dim3(6,1024), dim3(256), 0, stream>>>(X, 256, cwih_h, 256, bc_c, GI, 0, 256);
  // 11. GRUCell scan over T -> Hh bf16
  k_scan<true><<<dim3(64), dim3(512), 0, stream>>>(GI, nullptr, w8c, nullptr, c_bhh, nullptr, Hh);
  // 12. expand Hh -> out h field (f32)
  k_hout<<<dim3(16384), dim3(256), 0, stream>>>(Hh, out);
  // 13. actor: kT = [n][t][512]
  k_gemm<1,true,false><<<dim3(1024,4), dim3(256), 0, stream>>>(Hh, 256, actw_h, 256, actb, kT, 512, 256);
  // 14. logits + softmax
  k_logits<<<dim3(1024), dim3(256), 0, stream>>>(Kc, kT, out);
  // 15. a, v, one_hot(p)
  k_pack<<<dim3(32768), dim3(256), 0, stream>>>(actions, cw, cbi, out);
  // 16. second output = hx[-1:]
  hipMemcpyAsync(out + (size_t)128 * 1024 * 386, out + (size_t)127 * 1024 * 386,
                 (size_t)1024 * 386 * 4, hipMemcpyDeviceToDevice, stream);
}

// Round 7
// 1225.135 us; speedup vs baseline: 3.2713x; 1.0397x over previous
//
#include <hip/hip_runtime.h>

// T=128, N=1024, H=256, L=64, C=64, V=1000.
// R7: force Whh residency. R6 post-mortem: VGPR_Count=96 == sizeof(w8) proves
// the RA rematerialized the (noclobber) weight loads every step instead of
// keeping them live — launch_bounds min-waves is only a lower bound. Fix:
// opaque asm ties (asm ""(+v)) make the 48 fragments non-rematerializable.
// Also: hw packed converts (v_cvt_pk_bf16_f32 / v_cvt_pk_fp8_f32) replace
// ~96 inst/thread of software rounding in the gate epilogue.

typedef unsigned short u16;
typedef unsigned char u8;
typedef __attribute__((ext_vector_type(8))) short bf16x8;   // 8 bf16 = 4 VGPR
typedef __attribute__((ext_vector_type(4))) short bf16x4;   // 4 bf16 = 2 VGPR
typedef __attribute__((ext_vector_type(4))) float f32x4;
typedef __attribute__((ext_vector_type(2))) unsigned int u32x2;  // 8 fp8 = 2 VGPR

#define DEVFN static __device__ __forceinline__

DEVFN float b2f(u16 h){ union{unsigned u; float f;} v; v.u = ((unsigned)h) << 16; return v.f; }
DEVFN u16 f2b(float f){ union{float f; unsigned u;} v; v.f = f;
  return (u16)((v.u + 0x7fffu + ((v.u >> 16) & 1u)) >> 16); }

// f32 -> fp8 e4m3fn, denorm-correct (host-prep path for weights only)
DEVFN unsigned f2e4m3_full(float f){
  union{float ff; unsigned u;} v; v.ff = f;
  unsigned s = (v.u >> 31) << 7;
  int e = (int)((v.u >> 23) & 0xff) - 127;
  if (e < -10) return s;
  unsigned m = (v.u & 0x7fffff) | 0x800000;
  if (e < -6){
    int sh = 20 + (-6 - e);
    unsigned q = (m + (1u << (sh - 1))) >> sh;
    return s | q;
  }
  unsigned q = ((unsigned)(e + 7) << 3) | ((m & 0x7fffff) >> 20);
  q += (m >> 19) & 1u;
  if (q > 0x7e) q = 0x7e;
  return s | q;
}

DEVFN f32x4 mfma16(bf16x8 a, bf16x8 b, f32x4 c){
  asm("v_mfma_f32_16x16x32_bf16 %0, %1, %2, %0" : "+v"(c) : "v"(a), "v"(b));
  return c;
}
DEVFN f32x4 mfma8(u32x2 a, u32x2 b, f32x4 c){
  asm("v_mfma_f32_16x16x32_fp8_fp8 %0, %1, %2, %0" : "+v"(c) : "v"(a), "v"(b));
  return c;
}
DEVFN unsigned cvt_pk_bf16(float a, float b){
  unsigned r;
  asm("v_cvt_pk_bf16_f32 %0, %1, %2" : "=v"(r) : "v"(a), "v"(b));
  return r;
}
DEVFN unsigned cvt_pk_fp8(float a, float b){
  unsigned r;
  asm("v_cvt_pk_fp8_f32 %0, %1, %2" : "=v"(r) : "v"(a), "v"(b));
  return r;   // byte0 = fp8(a), byte1 = fp8(b)
}
DEVFN void gl_lds16(const void* g, void* l){
  __builtin_amdgcn_global_load_lds((const __attribute__((address_space(1))) void*)g,
                                   (__attribute__((address_space(3))) void*)l, 16, 0, 0);
}
DEVFN float sigm(float x){ return __builtin_amdgcn_rcpf(1.0f + __expf(-x)); }
DEVFN float tanhf_(float x){ float e = __expf(2.0f * x); return 1.0f - 2.0f * __builtin_amdgcn_rcpf(e + 1.0f); }

// ---------------- small converters / prep ----------------

__global__ __launch_bounds__(256) void k_f2b(const float* __restrict__ s, u16* __restrict__ d, int n){
  int i = blockIdx.x * 256 + threadIdx.x;
  if (i < n) d[i] = f2b(s[i]);
}

__global__ __launch_bounds__(256) void k_w8(const float* __restrict__ s, u8* __restrict__ d, int n){
  int i = blockIdx.x * 256 + threadIdx.x;
  if (i < n) d[i] = (u8)f2e4m3_full(s[i]);
}

__global__ __launch_bounds__(256) void k_bias(const float* __restrict__ bih, const float* __restrict__ bhh,
                                              float* __restrict__ dst){
  int i = blockIdx.x * 256 + threadIdx.x;
  if (i < 768) dst[i] = bih[i] + (i < 512 ? bhh[i] : 0.f);
}

// embedding gather, l-major: Mh2[l*1024+n][256]
__global__ __launch_bounds__(256) void k_embed(const float* __restrict__ emb, const int* __restrict__ lines,
                                               u16* __restrict__ Mh){
  int c = blockIdx.x * 256 + threadIdx.x;
  int row = c >> 5;
  int j = (c & 31) * 8;
  int ll = row >> 10, n = row & 1023;
  int line = lines[n * 64 + ll];
  const float* s = emb + line * 256 + j;
  bf16x8 v;
  #pragma unroll
  for (int q = 0; q < 8; q++) v[q] = (short)f2b(s[q]);
  *(bf16x8*)&Mh[row * 256 + j] = v;
}

// XA[t*N+n][0:64)=bf16(cond), [64:320)=Mh2[prev_action*1024+n]
__global__ __launch_bounds__(256) void k_xa(const float* __restrict__ cond, const u16* __restrict__ Mh2,
                                            const int* __restrict__ actions, u16* __restrict__ XA){
  int c = blockIdx.x * 256 + threadIdx.x;
  int tn = c / 40;
  int j = (c - tn * 40) * 8;
  bf16x8 v;
  if (j < 64){
    const float* s = cond + tn * 64 + j;
    #pragma unroll
    for (int q = 0; q < 8; q++) v[q] = (short)f2b(s[q]);
  } else {
    int t = tn >> 10, n = tn & 1023;
    int idx = t ? actions[(t - 1) * 1024 + n] : 0;   // p0 = one_hot(0)
    v = *(const bf16x8*)&Mh2[((size_t)idx * 1024 + n) * 256 + (j - 64)];
  }
  *(bf16x8*)&XA[tn * 320 + j] = v;
}

// ---------------- 128x128 NT GEMM, bf16 in/out, f32 acc ----------------
// MODE 0: plain. MODE 1: kT remap t*N+n -> n*128+t. MODE 2: scan-packed G.
template<int MODE, bool BIAS, bool RELU>
__global__ __launch_bounds__(256) void k_gemm(const u16* __restrict__ A, int lda,
                                              const u16* __restrict__ B, int ldb,
                                              const float* __restrict__ bias,
                                              u16* __restrict__ C, int ldc, int K){
  __shared__ __align__(16) u16 sA[4096], sB[4096];
  const int tid = threadIdx.x, wid = tid >> 6, l = tid & 63;
  const int l15 = l & 15, l4 = l >> 4;
  const int bxm = (MODE >= 2) ? blockIdx.y : blockIdx.x;
  const int bxn = (MODE >= 2) ? blockIdx.x : blockIdx.y;
  const int m0 = bxm * 128, n0 = bxn * 128;
  const int wm = (wid >> 1) * 64, wn = (wid & 1) * 64;
  const int srow = wid * 16 + (l >> 2), scol = (l & 3) * 8;
  f32x4 acc[4][4] = {};
  for (int k0 = 0; k0 < K; k0 += 32){
    gl_lds16(&A[(m0 + srow) * lda + k0 + scol],      (char*)sA + wid * 1024);
    gl_lds16(&A[(m0 + 64 + srow) * lda + k0 + scol], (char*)sA + 4096 + wid * 1024);
    gl_lds16(&B[(n0 + srow) * ldb + k0 + scol],      (char*)sB + wid * 1024);
    gl_lds16(&B[(n0 + 64 + srow) * ldb + k0 + scol], (char*)sB + 4096 + wid * 1024);
    __syncthreads();
    bf16x8 af[4], bfr[4];
    #pragma unroll
    for (int i = 0; i < 4; i++) af[i]  = *(const bf16x8*)&sA[(wm + i * 16 + l15) * 32 + l4 * 8];
    #pragma unroll
    for (int j = 0; j < 4; j++) bfr[j] = *(const bf16x8*)&sB[(wn + j * 16 + l15) * 32 + l4 * 8];
    #pragma unroll
    for (int i = 0; i < 4; i++)
      #pragma unroll
      for (int j = 0; j < 4; j++)
        acc[i][j] = mfma16(af[i], bfr[j], acc[i][j]);
    __syncthreads();
  }
  if constexpr (MODE >= 2){
    #pragma unroll
    for (int j = 0; j < 4; j++){
      int colp = wn + j * 16 + l15;
      float bia = BIAS ? bias[n0 + colp] : 0.f;
      size_t cpart = (size_t)blockIdx.x * 2048 + (size_t)(colp >> 4) * 256 + (size_t)(colp & 15) * 4;
      #pragma unroll
      for (int i = 0; i < 4; i++){
        int row = m0 + wm + i * 16 + l4 * 4;
        int t = row >> 10, n = row & 1023;
        size_t addr = ((size_t)t * 64 + (n >> 4)) * 12288 + (size_t)((n >> 2) & 3) * 64 + cpart;
        unsigned q0 = (unsigned)f2b(acc[i][j][0] + bia) | ((unsigned)f2b(acc[i][j][1] + bia) << 16);
        unsigned q1 = (unsigned)f2b(acc[i][j][2] + bia) | ((unsigned)f2b(acc[i][j][3] + bia) << 16);
        uint2 qq; qq.x = q0; qq.y = q1;
        *(uint2*)(C + addr) = qq;
      }
    }
  } else {
    #pragma unroll
    for (int i = 0; i < 4; i++)
      #pragma unroll
      for (int j = 0; j < 4; j++){
        int col = n0 + wn + j * 16 + l15;
        float bia = 0.f;
        if constexpr (BIAS) bia = bias[col];
        #pragma unroll
        for (int r = 0; r < 4; r++){
          int row = m0 + wm + i * 16 + l4 * 4 + r;
          float v = acc[i][j][r] + bia;
          if constexpr (RELU) v = fmaxf(v, 0.f);
          int orow = row;
          if constexpr (MODE == 1) orow = ((row & 1023) << 7) | (row >> 10);
          C[(size_t)orow * ldc + col] = f2b(v);
        }
      }
  }
}

// ---------------- GRU scans (fp8 matvec, register-resident Whh) ----------------

DEVFN int swz(int col, int row){ return ((((col >> 3) ^ (row & 7)) << 3) | (col & 7)); }

template<bool CELL>
__global__ __launch_bounds__(512, 2) void k_scan(
    const u16* __restrict__ Ga, const u16* __restrict__ Gbk,
    const u8* __restrict__ Wa, const u8* __restrict__ Wb,
    const float* __restrict__ bhha, const float* __restrict__ bhhb,
    u16* __restrict__ Ko)
{
  const int NSTEP = CELL ? 128 : 64;
  int dir = 0, nb = blockIdx.x;
  const u16 *G = Ga; const u8* W = Wa; const float* bhh = bhha;
  if (!CELL){
    dir = blockIdx.x & 1; nb = blockIdx.x >> 1;
    if (dir){ G = Gbk; W = Wb; bhh = bhhb; }
  }
  const int n0 = nb * 16;
  __shared__ __align__(16) u16 hbf[2][4096];
  __shared__ __align__(16) u8 hb8[2][4096];
  __shared__ __align__(16) u16 gib[2][12288];
  const int tid = threadIdx.x, wid = tid >> 6, l = tid & 63;
  const int l15 = l & 15, l4 = l >> 4;
  for (int i = tid; i < 4096; i += 512){ hbf[0][i] = 0; hb8[0][i] = 0; }
  const int col0 = wid * 16 + l15, col1 = col0 + 128;
  const float bhn0 = bhh[512 + col0], bhn1 = bhh[512 + col1];
  // resident fp8 weights — loaded once, then pinned via opaque asm so the RA
  // cannot rematerialize the (noclobber) loads inside the loop (R6 bug).
  u32x2 w8[3][2][8];
  #pragma unroll
  for (int g = 0; g < 3; g++)
    #pragma unroll
    for (int j = 0; j < 2; j++){
      const u8* wp = W + ((size_t)(g * 256 + (j ? col1 : col0)) * 256 + l4 * 8);
      #pragma unroll
      for (int kt = 0; kt < 8; kt++) w8[g][j][kt] = *(const u32x2*)&wp[kt * 32];
    }
  #pragma unroll
  for (int g = 0; g < 3; g++)
    #pragma unroll
    for (int j = 0; j < 2; j++)
      #pragma unroll
      for (int kt = 0; kt < 8; kt++)
        asm volatile("" : "+v"(w8[g][j][kt]));
  float h0[4] = {0.f,0.f,0.f,0.f}, h1[4] = {0.f,0.f,0.f,0.f};
  // cooperative output mapping: thread -> (row, phys 16B chunk) -> logical col
  const int orow = tid >> 5, oc8 = tid & 31;
  const int ocol = ((oc8 ^ (orow & 7)) << 3);
  {  // prologue: stage gi for first step
    int lc0 = (!CELL && dir) ? 63 : 0;
    const char* src = (const char*)(G + ((size_t)lc0 * 64 + nb) * 12288);
    #pragma unroll
    for (int q = 0; q < 3; q++)
      gl_lds16(src + (wid * 3 + q) * 1024 + l * 16, (char*)&gib[0][(wid * 3 + q) * 512]);
  }
  __syncthreads();
  int lc_prev = 0;
  #pragma unroll 1
  for (int s = 0; s < NSTEP; ++s){
    const int cb = s & 1;
    const int lc = CELL ? s : (dir ? 63 - s : s);
    const int sn = (s + 1 < NSTEP) ? s + 1 : s;
    const int lcn = CELL ? sn : (dir ? 63 - sn : sn);
    {  // stage next step's gi (3 vmem loads, issued FIRST)
      const char* src = (const char*)(G + ((size_t)lcn * 64 + nb) * 12288);
      #pragma unroll
      for (int q = 0; q < 3; q++)
        gl_lds16(src + (wid * 3 + q) * 1024 + l * 16, (char*)&gib[cb ^ 1][(wid * 3 + q) * 512]);
    }
    if (s > 0){  // cooperative store of previous step's h
      bf16x8 hv8 = *(const bf16x8*)&hbf[cb][tid * 8];
      if (CELL){
        *(bf16x8*)&Ko[((size_t)lc_prev * 1024 + n0 + orow) * 256 + ocol] = hv8;
      } else {
        *(bf16x8*)&Ko[((size_t)(n0 + orow) * 64 + lc_prev) * 512 + dir * 256 + ocol] = hv8;
      }
    }
    // A-fragments: fp8 h rows, 8B-chunk XOR swizzle
    u32x2 af8[8];
    #pragma unroll
    for (int kt = 0; kt < 8; kt++){
      int chunk = (kt * 4 + l4) ^ (l15 & 7);
      af8[kt] = *(const u32x2*)&hb8[cb][l15 * 256 + chunk * 8];
    }
    f32x4 a00={0,0,0,0}, a10={0,0,0,0}, a20={0,0,0,0};
    f32x4 a01={0,0,0,0}, a11={0,0,0,0}, a21={0,0,0,0};
    #pragma unroll
    for (int kt = 0; kt < 8; kt++){
      a00 = mfma8(af8[kt], w8[0][0][kt], a00);
      a10 = mfma8(af8[kt], w8[1][0][kt], a10);
      a20 = mfma8(af8[kt], w8[2][0][kt], a20);
      a01 = mfma8(af8[kt], w8[0][1][kt], a01);
      a11 = mfma8(af8[kt], w8[1][1][kt], a11);
      a21 = mfma8(af8[kt], w8[2][1][kt], a21);
    }
    // this step's gi
    bf16x4 y[6];
    #pragma unroll
    for (int yy = 0; yy < 6; yy++)
      y[yy] = *(const bf16x4*)&gib[cb][yy * 2048 + tid * 4];
    float hv0[4], hv1[4];
    #pragma unroll
    for (int r = 0; r < 4; r++){
      float rg = sigm(b2f((u16)y[0][r]) + a00[r]);
      float zg = sigm(b2f((u16)y[2][r]) + a10[r]);
      float nn = tanhf_(b2f((u16)y[4][r]) + rg * (a20[r] + bhn0));
      hv0[r] = (1.f - zg) * nn + zg * h0[r];
      h0[r] = hv0[r];
      float rg1 = sigm(b2f((u16)y[1][r]) + a01[r]);
      float zg1 = sigm(b2f((u16)y[3][r]) + a11[r]);
      float nn1 = tanhf_(b2f((u16)y[5][r]) + rg1 * (a21[r] + bhn1));
      hv1[r] = (1.f - zg1) * nn1 + zg1 * h1[r];
      h1[r] = hv1[r];
    }
    // packed hw converts -> LDS (2 values per cvt inst)
    #pragma unroll
    for (int p = 0; p < 2; p++){
      int rA = l4 * 4 + 2 * p, rB = rA + 1;
      unsigned bb0 = cvt_pk_bf16(hv0[2*p], hv0[2*p+1]);
      unsigned f80 = cvt_pk_fp8 (hv0[2*p], hv0[2*p+1]);
      int aA0 = rA * 256 + swz(col0, rA), aB0 = rB * 256 + swz(col0, rB);
      hbf[cb ^ 1][aA0] = (u16)bb0;  hbf[cb ^ 1][aB0] = (u16)(bb0 >> 16);
      hb8[cb ^ 1][aA0] = (u8)f80;   hb8[cb ^ 1][aB0] = (u8)(f80 >> 8);
      unsigned bb1 = cvt_pk_bf16(hv1[2*p], hv1[2*p+1]);
      unsigned f81 = cvt_pk_fp8 (hv1[2*p], hv1[2*p+1]);
      int aA1 = rA * 256 + swz(col1, rA), aB1 = rB * 256 + swz(col1, rB);
      hbf[cb ^ 1][aA1] = (u16)bb1;  hbf[cb ^ 1][aB1] = (u16)(bb1 >> 16);
      hb8[cb ^ 1][aA1] = (u8)f81;   hb8[cb ^ 1][aB1] = (u8)(f81 >> 8);
    }
    // sync: wait LDS + the 3 gl_lds; leave the store in flight (s>0)
    __builtin_amdgcn_sched_barrier(0);
    if (s == 0) asm volatile("s_waitcnt lgkmcnt(0) vmcnt(0)" ::: "memory");
    else        asm volatile("s_waitcnt lgkmcnt(0) vmcnt(1)" ::: "memory");
    __builtin_amdgcn_sched_barrier(0);
    __builtin_amdgcn_s_barrier();
    __builtin_amdgcn_sched_barrier(0);
    lc_prev = lc;
  }
  {  // epilogue: last step's h is in hbf[NSTEP&1]
    bf16x8 hv8 = *(const bf16x8*)&hbf[NSTEP & 1][tid * 8];
    if (CELL){
      *(bf16x8*)&Ko[((size_t)lc_prev * 1024 + n0 + orow) * 256 + ocol] = hv8;
    } else {
      *(bf16x8*)&Ko[((size_t)(n0 + orow) * 64 + lc_prev) * 512 + dir * 256 + ocol] = hv8;
    }
  }
}

// ---------------- Hh (bf16) -> out h field (f32) ----------------

__global__ __launch_bounds__(256) void k_hout(const u16* __restrict__ Hh, float* __restrict__ out){
  int c = blockIdx.x * 256 + threadIdx.x;
  int ro = c >> 5, j = (c & 31) * 8;
  bf16x8 v = *(const bf16x8*)&Hh[(size_t)ro * 256 + j];
  float* o = out + (size_t)ro * 386 + 2 + j;
  #pragma unroll
  for (int q = 0; q < 4; q++){
    float2 f; f.x = b2f((u16)v[q * 2]); f.y = b2f((u16)v[q * 2 + 1]);
    *(float2*)(o + q * 2) = f;
  }
}

// ---------------- per-n logits GEMM (128x64, K=512) + row softmax ----------------

__global__ __launch_bounds__(256) void k_logits(const u16* __restrict__ Kc, const u16* __restrict__ kT,
                                                float* __restrict__ out){
  int n = blockIdx.x;
  const int tid = threadIdx.x, wid = tid >> 6, l = tid & 63, l15 = l & 15, l4 = l >> 4;
  const u16* An = kT + n * 65536;    // [128 t][512]
  const u16* Bn = Kc + n * 32768;    // [64 l][512]
  f32x4 acc[2][4] = {};
  for (int kt = 0; kt < 16; ++kt){
    bf16x8 a0 = *(const bf16x8*)&An[(wid * 32 + l15) * 512 + kt * 32 + l4 * 8];
    bf16x8 a1 = *(const bf16x8*)&An[(wid * 32 + 16 + l15) * 512 + kt * 32 + l4 * 8];
    #pragma unroll
    for (int j = 0; j < 4; j++){
      bf16x8 b = *(const bf16x8*)&Bn[(j * 16 + l15) * 512 + kt * 32 + l4 * 8];
      acc[0][j] = mfma16(a0, b, acc[0][j]);
      acc[1][j] = mfma16(a1, b, acc[1][j]);
    }
  }
  #pragma unroll
  for (int i = 0; i < 2; i++)
    #pragma unroll
    for (int r = 0; r < 4; r++){
      float v0 = acc[i][0][r], v1 = acc[i][1][r], v2 = acc[i][2][r], v3 = acc[i][3][r];
      float mx = fmaxf(fmaxf(v0, v1), fmaxf(v2, v3));
      #pragma unroll
      for (int s2 = 1; s2 < 16; s2 <<= 1) mx = fmaxf(mx, __shfl_xor(mx, s2));
      float e0 = __expf(v0 - mx), e1 = __expf(v1 - mx), e2 = __expf(v2 - mx), e3 = __expf(v3 - mx);
      float sm = e0 + e1 + e2 + e3;
      #pragma unroll
      for (int s2 = 1; s2 < 16; s2 <<= 1) sm += __shfl_xor(sm, s2);
      float rs = __builtin_amdgcn_rcpf(sm);
      int t = wid * 32 + i * 16 + l4 * 4 + r;
      float* o = out + (size_t)(t * 1024 + n) * 386 + 258;
      o[l15] = e0 * rs; o[16 + l15] = e1 * rs; o[32 + l15] = e2 * rs; o[48 + l15] = e3 * rs;
    }
}

// ---------------- a, v=critic(h), p=one_hot ----------------

__global__ __launch_bounds__(256) void k_pack(const int* __restrict__ actions,
                                              const float* __restrict__ cw, const float* __restrict__ cb,
                                              float* __restrict__ out){
  int idx = blockIdx.x * 4 + (threadIdx.x >> 6);
  int l = threadIdx.x & 63;
  float* o = out + (size_t)idx * 386;
  float s = 0.f;
  #pragma unroll
  for (int q = 0; q < 4; q++) s += o[2 + l + q * 64] * cw[l + q * 64];
  #pragma unroll
  for (int m = 32; m; m >>= 1) s += __shfl_down(s, m);
  int a = actions[idx];
  if (l == 0){ o[0] = (float)a; o[1] = s + cb[0]; }
  o[322 + l] = (l == a) ? 1.0f : 0.0f;
}

// ---------------- host ----------------

extern "C" void kernel_launch(void* const* d_in, const int* in_sizes, int n_in,
                              void* d_out, int out_size, void* d_ws, size_t ws_size,
                              hipStream_t stream){
  (void)in_sizes; (void)n_in; (void)out_size; (void)ws_size;
  const float* cond  = (const float*)d_in[0];
  const float* emb   = (const float*)d_in[1];
  const float* wih_f = (const float*)d_in[2];
  const float* whh_f = (const float*)d_in[3];
  const float* bih_f = (const float*)d_in[4];
  const float* bhh_f = (const float*)d_in[5];
  const float* wih_b = (const float*)d_in[6];
  const float* whh_b = (const float*)d_in[7];
  const float* bih_b = (const float*)d_in[8];
  const float* bhh_b = (const float*)d_in[9];
  const float* f_w0  = (const float*)d_in[10];
  const float* f_b0  = (const float*)d_in[11];
  const float* f_w1  = (const float*)d_in[12];
  const float* f_b1  = (const float*)d_in[13];
  const float* c_wih = (const float*)d_in[14];
  const float* c_whh = (const float*)d_in[15];
  const float* c_bih = (const float*)d_in[16];
  const float* c_bhh = (const float*)d_in[17];
  const float* actw  = (const float*)d_in[18];
  const float* actb  = (const float*)d_in[19];
  const float* cw    = (const float*)d_in[20];
  const float* cbi   = (const float*)d_in[21];
  const int* lines   = (const int*)d_in[22];
  const int* actions = (const int*)d_in[23];
  float* out = (float*)d_out;

  char* ws = (char*)d_ws;
  size_t off = 0;
  auto alloc = [&](size_t b){ char* p = ws + off; off += (b + 255) & ~(size_t)255; return p; };
  u16* Kc  = (u16*)alloc((size_t)1024 * 64 * 512 * 2);   // 64 MiB
  char* RA = alloc((size_t)128 * 1024 * 768 * 2);        // 192 MiB: Gf|Gb -> GI -> kT
  char* RD = alloc((size_t)128 * 1024 * 320 * 2);        // 80 MiB:  XA -> X -> Hh
  u16* X0  = (u16*)alloc((size_t)128 * 1024 * 256 * 2);  // 64 MiB (Mh2 early, then MLP mid)
  u16* wihf_h = (u16*)alloc(196608 * 2);
  u16* wihb_h = (u16*)alloc(196608 * 2);
  u16* cwih_h = (u16*)alloc(196608 * 2);
  u16* fw0_h  = (u16*)alloc(81920 * 2);
  u16* fw1_h  = (u16*)alloc(65536 * 2);
  u16* actw_h = (u16*)alloc(131072 * 2);
  u8* w8f = (u8*)alloc(196608);
  u8* w8b = (u8*)alloc(196608);
  u8* w8c = (u8*)alloc(196608);
  float* bc_f = (float*)alloc(768 * 4);
  float* bc_b = (float*)alloc(768 * 4);
  float* bc_c = (float*)alloc(768 * 4);

  u16* Gf  = (u16*)RA;                                   // packed [l][nb][...] 96 MiB
  u16* Gb  = (u16*)(RA + (size_t)64 * 1024 * 768 * 2);
  u16* GI  = (u16*)RA;                                   // packed [t][nb][...] 192 MiB
  u16* kT  = (u16*)RA;
  u16* XA  = (u16*)RD;
  u16* X   = (u16*)RD;
  u16* Hh  = (u16*)RD;
  u16* Mh2 = X0;                                          // l-major embeddings

  // 1. GEMM weights -> bf16; recurrent weights -> fp8 e4m3
  const float* srcs[6] = {wih_f, wih_b, c_wih, f_w0, f_w1, actw};
  u16* dsts[6] = {wihf_h, wihb_h, cwih_h, fw0_h, fw1_h, actw_h};
  const int ns[6] = {196608,196608,196608,81920,65536,131072};
  for (int i = 0; i < 6; i++)
    k_f2b<<<dim3((ns[i] + 255) / 256), dim3(256), 0, stream>>>(srcs[i], dsts[i], ns[i]);
  k_w8<<<dim3(768), dim3(256), 0, stream>>>(whh_f, w8f, 196608);
  k_w8<<<dim3(768), dim3(256), 0, stream>>>(whh_b, w8b, 196608);
  k_w8<<<dim3(768), dim3(256), 0, stream>>>(c_whh, w8c, 196608);
  // 2. combined biases
  k_bias<<<dim3(3), dim3(256), 0, stream>>>(bih_f, bhh_f, bc_f);
  k_bias<<<dim3(3), dim3(256), 0, stream>>>(bih_b, bhh_b, bc_b);
  k_bias<<<dim3(3), dim3(256), 0, stream>>>(c_bih, c_bhh, bc_c);
  // 3. embedding gather (l-major)
  k_embed<<<dim3(8192), dim3(256), 0, stream>>>(emb, lines, Mh2);
  // 4/5. line-GRU input projections -> packed Gf/Gb (bias folded)
  k_gemm<2,true,false><<<dim3(6,512), dim3(256), 0, stream>>>(Mh2, 256, wihf_h, 256, bc_f, Gf, 0, 256);
  k_gemm<2,true,false><<<dim3(6,512), dim3(256), 0, stream>>>(Mh2, 256, wihb_h, 256, bc_b, Gb, 0, 256);
  // 6. bidirectional line-GRU scan -> Kc
  k_scan<false><<<dim3(128), dim3(512), 0, stream>>>(Gf, Gb, w8f, w8b, bhh_f, bhh_b, Kc);
  // 7. pointer-read gather + cond concat
  k_xa<<<dim3(20480), dim3(256), 0, stream>>>(cond, Mh2, actions, XA);
  // 8/9. MLP
  k_gemm<0,true,true><<<dim3(1024,2), dim3(256), 0, stream>>>(XA, 320, fw0_h, 320, f_b0, X0, 256, 320);
  k_gemm<0,true,true><<<dim3(1024,2), dim3(256), 0, stream>>>(X0, 256, fw1_h, 256, f_b1, X, 256, 256);
  // 10. GRUCell input projections -> packed GI (bias folded)
  k_gemm<2,true,false><<<dim3(6,1024), dim3(256), 0, stream>>>(X, 256, cwih_h, 256, bc_c, GI, 0, 256);
  // 11. GRUCell scan over T -> Hh bf16
  k_scan<true><<<dim3(64), dim3(512), 0, stream>>>(GI, nullptr, w8c, nullptr, c_bhh, nullptr, Hh);
  // 12. expand Hh -> out h field (f32)
  k_hout<<<dim3(16384), dim3(256), 0, stream>>>(Hh, out);
  // 13. actor: kT = [n][t][512]
  k_gemm<1,true,false><<<dim3(1024,4), dim3(256), 0, stream>>>(Hh, 256, actw_h, 256, actb, kT, 512, 256);
  // 14. logits + softmax
  k_logits<<<dim3(1024), dim3(256), 0, stream>>>(Kc, kT, out);
  // 15. a, v, one_hot(p)
  k_pack<<<dim3(32768), dim3(256), 0, stream>>>(actions, cw, cbi, out);
  // 16. second output = hx[-1:]
  hipMemcpyAsync(out + (size_t)128 * 1024 * 386, out + (size_t)127 * 1024 * 386,
                 (size_t)1024 * 386 * 4, hipMemcpyDeviceToDevice, stream);
}